// Round 1
// baseline (1114.257 us; speedup 1.0000x reference)
//
#include <hip/hip_runtime.h>
#include <math.h>

// CrossAttention: B=2,S=2048,E=1024,H=16,Dh=64,NC=768, fp32 in/out.
// R1: correct fp32 baseline. GEMMs: 64x64 tile, 4x4 reg blocking, LDS-staged.
// Attention: flash-style, one block per (b,h,64-row q-tile), online softmax.
// ws layout: q[B,H,S,Dh] | k[..] | v[..] | attn_out[B,S,E]  (4 x 16 MB = 64 MB)

namespace {

constexpr int B  = 2;
constexpr int S  = 2048;
constexpr int E  = 1024;
constexpr int NC = 768;
constexpr int H  = 16;
constexpr int DH = 64;

// C[M,N] = A[M,K] @ W[K,N] + bias[N]
// SPLIT_HEADS: write C to [B,H,S,DH] layout instead of [M,N].
template <bool SPLIT_HEADS>
__global__ __launch_bounds__(256) void gemm_bias(
    const float* __restrict__ A, const float* __restrict__ W,
    const float* __restrict__ bias, float* __restrict__ C,
    int M, int N, int K) {
    __shared__ float As[16][68];  // [k][m]  (transposed A-tile, +4 pad, 16B-aligned rows)
    __shared__ float Bs[16][68];  // [k][n]

    const int tx = threadIdx.x, ty = threadIdx.y;
    const int t  = ty * 16 + tx;
    const int n0 = blockIdx.x * 64;
    const int m0 = blockIdx.y * 64;

    const int ar  = t >> 2;          // 0..63 : A tile row
    const int ac4 = (t & 3) << 2;    // 0,4,8,12 : A tile k-col (float4)
    const int br  = t >> 4;          // 0..15 : W tile k-row
    const int bc4 = (t & 15) << 2;   // 0..60 : W tile n-col (float4)

    float acc[4][4] = {};

    for (int kt = 0; kt < K; kt += 16) {
        float4 av = *(const float4*)&A[(size_t)(m0 + ar) * K + kt + ac4];
        float4 bv = *(const float4*)&W[(size_t)(kt + br) * N + n0 + bc4];
        __syncthreads();  // previous tile fully consumed
        As[ac4 + 0][ar] = av.x;  // transpose scatter: 2-way banks, free
        As[ac4 + 1][ar] = av.y;
        As[ac4 + 2][ar] = av.z;
        As[ac4 + 3][ar] = av.w;
        *(float4*)&Bs[br][bc4] = bv;
        __syncthreads();
#pragma unroll
        for (int kk = 0; kk < 16; ++kk) {
            float4 a4 = *(const float4*)&As[kk][ty << 2];  // ds_read_b128, broadcast
            float4 b4 = *(const float4*)&Bs[kk][tx << 2];  // ds_read_b128, 2-way
            const float aa[4] = {a4.x, a4.y, a4.z, a4.w};
            const float bb[4] = {b4.x, b4.y, b4.z, b4.w};
#pragma unroll
            for (int i = 0; i < 4; ++i)
#pragma unroll
                for (int j = 0; j < 4; ++j)
                    acc[i][j] = fmaf(aa[i], bb[j], acc[i][j]);
        }
    }

    float4 bvv = *(const float4*)&bias[n0 + (tx << 2)];
    const float bb[4] = {bvv.x, bvv.y, bvv.z, bvv.w};
#pragma unroll
    for (int i = 0; i < 4; ++i) {
        const int gm = m0 + (ty << 2) + i;
        float4 o;
        o.x = acc[i][0] + bb[0];
        o.y = acc[i][1] + bb[1];
        o.z = acc[i][2] + bb[2];
        o.w = acc[i][3] + bb[3];
        if (SPLIT_HEADS) {
            // n-tile spans exactly one head (n0 % 64 == 0, tile = 64)
            const int bb_ = gm / S, ss = gm % S;
            const int hh  = n0 >> 6;
            const size_t idx =
                (((size_t)bb_ * H + hh) * S + ss) * DH + (tx << 2);
            *(float4*)&C[idx] = o;
        } else {
            *(float4*)&C[(size_t)gm * N + n0 + (tx << 2)] = o;
        }
    }
}

// Flash attention. Q,K,V in [B,H,S,DH]; O written to [B,S,E] (heads merged).
// Block = 256 threads = (16,16); one block per (b, h, 64-row q-tile).
__global__ __launch_bounds__(256) void attention(
    const float* __restrict__ Q, const float* __restrict__ Kin,
    const float* __restrict__ V, float* __restrict__ O) {
    __shared__ float Qs[64][68];   // [d][r]   (Q^T for b128 fragment reads)
    __shared__ float KPs[64][68];  // scores phase: [d][c] = K^T; PV phase: [r][c] = P
    __shared__ float Vs[64][68];   // [c][d]

    const int tx = threadIdx.x, ty = threadIdx.y;
    const int t  = ty * 16 + tx;

    const int bid = blockIdx.x;
    const int b   = bid / (H * (S / 64));
    const int rem = bid % (H * (S / 64));
    const int h   = rem / (S / 64);
    const int qt  = rem % (S / 64);

    const float* qp = Q + (((size_t)b * H + h) * S + (size_t)qt * 64) * DH;
    const float* kp = Kin + (((size_t)b * H + h) * S) * DH;
    const float* vp = V + (((size_t)b * H + h) * S) * DH;

    const int lr  = t >> 4;         // 0..15
    const int ld4 = (t & 15) << 2;  // 0..60

    // Q tile -> Qs[d][r] (transposed); loaded once per block
#pragma unroll
    for (int rep = 0; rep < 4; ++rep) {
        const int r = lr + rep * 16;
        float4 q4  = *(const float4*)&qp[(size_t)r * DH + ld4];
        Qs[ld4 + 0][r] = q4.x;
        Qs[ld4 + 1][r] = q4.y;
        Qs[ld4 + 2][r] = q4.z;
        Qs[ld4 + 3][r] = q4.w;
    }

    float m_run[4], l_run[4];
    float o[4][4] = {};
#pragma unroll
    for (int i = 0; i < 4; ++i) {
        m_run[i] = -INFINITY;
        l_run[i] = 0.f;
    }

    for (int kt0 = 0; kt0 < S; kt0 += 64) {
        __syncthreads();  // previous PV done with KPs/Vs (also covers Qs writes)
#pragma unroll
        for (int rep = 0; rep < 4; ++rep) {
            const int r = lr + rep * 16;
            float4 k4  = *(const float4*)&kp[(size_t)(kt0 + r) * DH + ld4];
            KPs[ld4 + 0][r] = k4.x;  // K^T scatter
            KPs[ld4 + 1][r] = k4.y;
            KPs[ld4 + 2][r] = k4.z;
            KPs[ld4 + 3][r] = k4.w;
            float4 v4 = *(const float4*)&vp[(size_t)(kt0 + r) * DH + ld4];
            *(float4*)&Vs[r][ld4] = v4;
        }
        __syncthreads();

        // scores: sc[i][j] = 0.125 * sum_d Q[r][d] * K[c][d]
        float sc[4][4] = {};
#pragma unroll 16
        for (int d = 0; d < 64; ++d) {
            float4 q4 = *(const float4*)&Qs[d][ty << 2];
            float4 k4 = *(const float4*)&KPs[d][tx << 2];
            const float qa[4] = {q4.x, q4.y, q4.z, q4.w};
            const float ka[4] = {k4.x, k4.y, k4.z, k4.w};
#pragma unroll
            for (int i = 0; i < 4; ++i)
#pragma unroll
                for (int j = 0; j < 4; ++j)
                    sc[i][j] = fmaf(qa[i], ka[j], sc[i][j]);
        }

        // online softmax (row reduction across the 16 tx-lanes of each ty group)
#pragma unroll
        for (int i = 0; i < 4; ++i) {
#pragma unroll
            for (int j = 0; j < 4; ++j) sc[i][j] *= 0.125f;
            float mx = fmaxf(fmaxf(sc[i][0], sc[i][1]), fmaxf(sc[i][2], sc[i][3]));
#pragma unroll
            for (int msk = 1; msk < 16; msk <<= 1)
                mx = fmaxf(mx, __shfl_xor(mx, msk));
            const float m_new = fmaxf(m_run[i], mx);
            const float alpha = __expf(m_run[i] - m_new);
            m_run[i] = m_new;
            float rs = 0.f;
#pragma unroll
            for (int j = 0; j < 4; ++j) {
                sc[i][j] = __expf(sc[i][j] - m_new);
                rs += sc[i][j];
            }
#pragma unroll
            for (int msk = 1; msk < 16; msk <<= 1)
                rs += __shfl_xor(rs, msk);
            l_run[i] = l_run[i] * alpha + rs;
#pragma unroll
            for (int j = 0; j < 4; ++j) o[i][j] *= alpha;
        }

        __syncthreads();  // all threads done reading KPs as K^T
#pragma unroll
        for (int i = 0; i < 4; ++i)
            *(float4*)&KPs[(ty << 2) + i][tx << 2] =
                make_float4(sc[i][0], sc[i][1], sc[i][2], sc[i][3]);
        __syncthreads();

        // O += P @ V
#pragma unroll 4
        for (int c4 = 0; c4 < 64; c4 += 4) {
            float4 p4[4];
#pragma unroll
            for (int i = 0; i < 4; ++i)
                p4[i] = *(const float4*)&KPs[(ty << 2) + i][c4];
#pragma unroll
            for (int cc = 0; cc < 4; ++cc) {
                float4 v4 = *(const float4*)&Vs[c4 + cc][tx << 2];
                const float va[4] = {v4.x, v4.y, v4.z, v4.w};
#pragma unroll
                for (int i = 0; i < 4; ++i) {
                    const float pv = ((const float*)&p4[i])[cc];
#pragma unroll
                    for (int j = 0; j < 4; ++j)
                        o[i][j] = fmaf(pv, va[j], o[i][j]);
                }
            }
        }
    }

    // epilogue: normalize and write merged-head layout [B,S,E]
    float* op = O + ((size_t)b * S + (size_t)qt * 64) * E + h * DH;
#pragma unroll
    for (int i = 0; i < 4; ++i) {
        const int r      = (ty << 2) + i;
        const float inv  = 1.f / l_run[i];
        float4 st = make_float4(o[i][0] * inv, o[i][1] * inv,
                                o[i][2] * inv, o[i][3] * inv);
        *(float4*)&op[(size_t)r * E + (tx << 2)] = st;
    }
}

}  // namespace

extern "C" void kernel_launch(void* const* d_in, const int* in_sizes, int n_in,
                              void* d_out, int out_size, void* d_ws,
                              size_t ws_size, hipStream_t stream) {
    const float* x   = (const float*)d_in[0];
    const float* ctx = (const float*)d_in[1];
    const float* Wq  = (const float*)d_in[2];
    const float* bq  = (const float*)d_in[3];
    const float* Wk  = (const float*)d_in[4];
    const float* bk  = (const float*)d_in[5];
    const float* Wv  = (const float*)d_in[6];
    const float* bv  = (const float*)d_in[7];
    const float* Wo  = (const float*)d_in[8];
    const float* bo  = (const float*)d_in[9];
    float* out = (float*)d_out;

    const size_t per = (size_t)B * H * S * DH;  // 4,194,304 floats
    float* q_ws = (float*)d_ws;
    float* k_ws = q_ws + per;
    float* v_ws = k_ws + per;
    float* ao   = v_ws + per;  // total 64 MB of ws

    const int M = B * S;  // 4096
    dim3 blk(16, 16);
    dim3 gg(E / 64, M / 64);  // (16, 64)

    gemm_bias<true><<<gg, blk, 0, stream>>>(x, Wq, bq, q_ws, M, E, E);
    gemm_bias<true><<<gg, blk, 0, stream>>>(ctx, Wk, bk, k_ws, M, E, NC);
    gemm_bias<true><<<gg, blk, 0, stream>>>(ctx, Wv, bv, v_ws, M, E, NC);
    attention<<<B * H * (S / 64), blk, 0, stream>>>(q_ws, k_ws, v_ws, ao);
    gemm_bias<false><<<gg, blk, 0, stream>>>(ao, Wo, bo, out, M, E, E);
}

// Round 2
// 362.528 us; speedup vs baseline: 3.0736x; 3.0736x over previous
//
#include <hip/hip_runtime.h>
#include <math.h>

// CrossAttention B=2,S=2048,E=1024,H=16,Dh=64,NC=768 — fp32 in/out.
// R2: full bf16 MFMA rewrite (v_mfma_f32_32x32x16_bf16).
//  - prep: convert x/ctx to bf16; transpose+convert weights to Wt[N][K] bf16
//  - 4 GEMMs: no-LDS direct-global fragment loads, wave tile 64x64 (2x2 of 32x32)
//  - attention: barrier-free flash, S^T=K@Q^T formulation (in-lane softmax),
//    P^T built via one cross-half shuffle, O^T accumulated, no LDS/sync.
// Error budget: sigma_ao~0.04 => all bf16 rounding paths ~1e-4 abs in output.

namespace {

constexpr int S = 2048;
constexpr int E = 1024;

typedef short bfr  __attribute__((ext_vector_type(8)));   // 8 bf16 = 4 VGPR
typedef short s4v  __attribute__((ext_vector_type(4)));
typedef float accf __attribute__((ext_vector_type(16)));  // 32x32 C/D frag

#define MFMA32(a, b, c) __builtin_amdgcn_mfma_f32_32x32x16_bf16(a, b, c, 0, 0, 0)

__device__ inline short f2bf(float f) {  // RNE float->bf16 (raw bits)
    unsigned u = __float_as_uint(f);
    u += 0x7fffu + ((u >> 16) & 1u);
    return (short)(u >> 16);
}

__device__ inline accf zero16() {
    accf z;
#pragma unroll
    for (int i = 0; i < 16; ++i) z[i] = 0.f;
    return z;
}

// ---------- prep: fp32 -> bf16 elementwise ----------
__global__ __launch_bounds__(256) void tobf(const float* __restrict__ in,
                                            short* __restrict__ out, int n4) {
    int i = blockIdx.x * 256 + threadIdx.x;
    if (i < n4) {
        float4 v = ((const float4*)in)[i];
        s4v p = {f2bf(v.x), f2bf(v.y), f2bf(v.z), f2bf(v.w)};
        ((s4v*)out)[i] = p;
    }
}

// ---------- prep: W[K][N] fp32 -> Wt[N][K] bf16 (64x64 LDS tiles) ----------
__global__ __launch_bounds__(256) void wtrans(const float* __restrict__ W,
                                              short* __restrict__ Wt,
                                              int K, int N) {
    __shared__ short t[64][68];
    const int tid = threadIdx.x;
    const int k0 = blockIdx.y * 64, n0 = blockIdx.x * 64;
    const int kr = tid >> 4, nc = (tid & 15) * 4;
#pragma unroll
    for (int rep = 0; rep < 4; ++rep) {
        int k = kr + rep * 16;
        float4 v = *(const float4*)&W[(size_t)(k0 + k) * N + n0 + nc];
        t[nc + 0][k] = f2bf(v.x);
        t[nc + 1][k] = f2bf(v.y);
        t[nc + 2][k] = f2bf(v.z);
        t[nc + 3][k] = f2bf(v.w);
    }
    __syncthreads();
    const int nr = tid >> 4, kc = (tid & 15) * 4;
#pragma unroll
    for (int rep = 0; rep < 4; ++rep) {
        int n = nr + rep * 16;
        s4v p = {t[n][kc], t[n][kc + 1], t[n][kc + 2], t[n][kc + 3]};
        *(s4v*)&Wt[(size_t)(n0 + n) * K + k0 + kc] = p;
    }
}

// ---------- bf16 GEMM: C[m][n] = A[m][:] @ Wt[n][:] (+bias)*scale ----------
// A [M,K] bf16 row-major; Bt [N=1024,K] bf16 row-major. Block 128 thr = 2 waves,
// tile 128(M)x64(N), wave tile 64x64 = 2x2 frags of 32x32x16. No LDS.
// MODE 0: bf16 out flat [M,1024]. MODE 1: V^T bf16 [B,H,64,S]. MODE 2: fp32 [M,1024].
template <int MODE>
__global__ __launch_bounds__(128) void gemm_bf16(
    const short* __restrict__ A, const short* __restrict__ Bt,
    const float* __restrict__ bias, void* __restrict__ out,
    int K, float scale) {
    const int lane = threadIdx.x & 63;
    const int wv   = threadIdx.x >> 6;
    const int lm = lane & 31, h2 = lane >> 5;
    const int m0 = blockIdx.y * 128 + wv * 64;
    const int n0 = blockIdx.x * 64;

    const short* a0 = A + (size_t)(m0 + lm) * K + h2 * 8;
    const short* a1 = a0 + (size_t)32 * K;
    const short* b0 = Bt + (size_t)(n0 + lm) * K + h2 * 8;
    const short* b1 = b0 + (size_t)32 * K;

    accf acc[2][2] = {zero16(), zero16(), zero16(), zero16()};

    for (int kt = 0; kt < K; kt += 32) {
        bfr af0 = *(const bfr*)(a0 + kt);
        bfr af0b = *(const bfr*)(a0 + kt + 16);
        bfr af1 = *(const bfr*)(a1 + kt);
        bfr af1b = *(const bfr*)(a1 + kt + 16);
        bfr bf0 = *(const bfr*)(b0 + kt);
        bfr bf0b = *(const bfr*)(b0 + kt + 16);
        bfr bf1 = *(const bfr*)(b1 + kt);
        bfr bf1b = *(const bfr*)(b1 + kt + 16);
        acc[0][0] = MFMA32(af0, bf0, acc[0][0]);
        acc[0][1] = MFMA32(af0, bf1, acc[0][1]);
        acc[1][0] = MFMA32(af1, bf0, acc[1][0]);
        acc[1][1] = MFMA32(af1, bf1, acc[1][1]);
        acc[0][0] = MFMA32(af0b, bf0b, acc[0][0]);
        acc[0][1] = MFMA32(af0b, bf1b, acc[0][1]);
        acc[1][0] = MFMA32(af1b, bf0b, acc[1][0]);
        acc[1][1] = MFMA32(af1b, bf1b, acc[1][1]);
    }

#pragma unroll
    for (int nt = 0; nt < 2; ++nt) {
        const int n = n0 + nt * 32 + lm;
        const float bn = bias[n];
#pragma unroll
        for (int mt = 0; mt < 2; ++mt) {
            if (MODE == 1) {
                // V^T: n -> (h,d); m -> (b,s); regs 4g..4g+3 are consecutive s
                const int h = n >> 6, d = n & 63;
#pragma unroll
                for (int g = 0; g < 4; ++g) {
                    const int m = m0 + mt * 32 + 4 * h2 + 8 * g;
                    const int bb = m >> 11, s = m & 2047;
                    float v0 = (acc[mt][nt][4 * g + 0] + bn) * scale;
                    float v1 = (acc[mt][nt][4 * g + 1] + bn) * scale;
                    float v2 = (acc[mt][nt][4 * g + 2] + bn) * scale;
                    float v3 = (acc[mt][nt][4 * g + 3] + bn) * scale;
                    s4v p = {f2bf(v0), f2bf(v1), f2bf(v2), f2bf(v3)};
                    *(s4v*)((short*)out +
                            ((size_t)((bb * 16 + h) * 64 + d)) * 2048 + s) = p;
                }
            } else {
#pragma unroll
                for (int r = 0; r < 16; ++r) {
                    const int m = m0 + mt * 32 + 4 * h2 + (r & 3) + 8 * (r >> 2);
                    float v = (acc[mt][nt][r] + bn) * scale;
                    if (MODE == 0)
                        ((short*)out)[(size_t)m * 1024 + n] = f2bf(v);
                    else
                        ((float*)out)[(size_t)m * 1024 + n] = v;
                }
            }
        }
    }
}

// ---------- flash attention, barrier-free, S^T formulation ----------
// Qf,Kf flat [4096,1024] bf16 (Q pre-scaled by 0.125); Vt [B,H,64,S] bf16.
// Block 256 = 4 waves; wave owns 32 q-rows; grid bid = qb*32 + (b*16+h)
// (same head -> same XCD for L2 KV reuse).
__global__ __launch_bounds__(256) void attn(const short* __restrict__ Qf,
                                            const short* __restrict__ Kf,
                                            const short* __restrict__ Vt,
                                            short* __restrict__ ao) {
    const int bid = blockIdx.x;
    const int hidx = bid & 31;  // b*16+h
    const int qb   = bid >> 5;  // 0..15
    const int b = hidx >> 4, h = hidx & 15;
    const int lane = threadIdx.x & 63;
    const int wv   = threadIdx.x >> 6;
    const int lm = lane & 31;
    const int h2 = lane >> 5;
    const bool hb = h2 != 0;
    const int q0 = qb * 128 + wv * 32;

    // Q B-frags (Bt rows = Q[q][d], q = lm), cached for whole block
    const short* qp = Qf + (size_t)(b * 2048 + q0 + lm) * 1024 + h * 64 + h2 * 8;
    bfr qf[4];
#pragma unroll
    for (int kc = 0; kc < 4; ++kc) qf[kc] = *(const bfr*)(qp + kc * 16);

    const short* kb = Kf + (size_t)(b * 2048) * 1024 + h * 64 + h2 * 8;
    const short* vb = Vt + ((size_t)(hidx * 64 + lm)) * 2048 + h2 * 8;

    accf oa0 = zero16(), oa1 = zero16();  // O^T[d][q], d-tiles 0/1
    float m_run = -3.4e38f, l_run = 0.f;

    for (int kt = 0; kt < 2048; kt += 64) {
        // K A-frags: A[m=kv][k=d]
        bfr kf0[4], kf1[4];
        const short* k0p = kb + (size_t)(kt + lm) * 1024;
        const short* k1p = k0p + (size_t)32 * 1024;
#pragma unroll
        for (int kc = 0; kc < 4; ++kc) {
            kf0[kc] = *(const bfr*)(k0p + kc * 16);
            kf1[kc] = *(const bfr*)(k1p + kc * 16);
        }
        accf s0 = zero16(), s1 = zero16();
#pragma unroll
        for (int kc = 0; kc < 4; ++kc) {
            s0 = MFMA32(kf0[kc], qf[kc], s0);
            s1 = MFMA32(kf1[kc], qf[kc], s1);
        }
        // V^T A-frags: A[m=d][k=kv] — issue early, consumed after softmax
        bfr vf0[4], vf1[4];
#pragma unroll
        for (int kc = 0; kc < 4; ++kc) {
            vf0[kc] = *(const bfr*)(vb + kt + kc * 16);
            vf1[kc] = *(const bfr*)(vb + (size_t)32 * 2048 + kt + kc * 16);
        }

        // online softmax over kv (rows): in-lane regs + one cross-half shuffle
        float mx = s0[0];
#pragma unroll
        for (int i = 1; i < 16; ++i) mx = fmaxf(mx, s0[i]);
#pragma unroll
        for (int i = 0; i < 16; ++i) mx = fmaxf(mx, s1[i]);
        mx = fmaxf(mx, __shfl_xor(mx, 32));
        const float mnew = fmaxf(m_run, mx);
        const float alpha = __expf(m_run - mnew);
        float rs = 0.f;
#pragma unroll
        for (int i = 0; i < 16; ++i) {
            s0[i] = __expf(s0[i] - mnew);
            rs += s0[i];
        }
#pragma unroll
        for (int i = 0; i < 16; ++i) {
            s1[i] = __expf(s1[i] - mnew);
            rs += s1[i];
        }
        rs += __shfl_xor(rs, 32);
        l_run = l_run * alpha + rs;
        m_run = mnew;
#pragma unroll
        for (int i = 0; i < 16; ++i) {
            oa0[i] *= alpha;
            oa1[i] *= alpha;
        }

        // build P^T B-frags from S^T C-layout: one shfl_xor(32) per 4 elems
        bfr pb[4];
#pragma unroll
        for (int kc = 0; kc < 4; ++kc) {
            const int base = 8 * (kc & 1);
            float e[8];
#pragma unroll
            for (int i = 0; i < 4; ++i) {
                float lo = (kc < 2) ? s0[base + i] : s1[base + i];
                float hi = (kc < 2) ? s0[base + 4 + i] : s1[base + 4 + i];
                float own = hb ? hi : lo;
                float con = hb ? lo : hi;
                float rcv = __shfl_xor(con, 32);
                e[i]     = hb ? rcv : own;
                e[4 + i] = hb ? own : rcv;
            }
            bfr p;
#pragma unroll
            for (int j = 0; j < 8; ++j) p[j] = f2bf(e[j]);
            pb[kc] = p;
        }

        // O^T += V^T @ P^T
#pragma unroll
        for (int kc = 0; kc < 4; ++kc) {
            oa0 = MFMA32(vf0[kc], pb[kc], oa0);
            oa1 = MFMA32(vf1[kc], pb[kc], oa1);
        }
    }

    // epilogue: normalize, write ao flat [4096][1024] bf16 (8B packed stores)
    const float inv = 1.f / l_run;
    short* orow = ao + (size_t)(b * 2048 + q0 + lm) * 1024 + h * 64;
#pragma unroll
    for (int dt = 0; dt < 2; ++dt) {
        const accf& oa = dt ? oa1 : oa0;
#pragma unroll
        for (int g = 0; g < 4; ++g) {
            const int d0 = dt * 32 + 4 * h2 + 8 * g;
            s4v p = {f2bf(oa[4 * g + 0] * inv), f2bf(oa[4 * g + 1] * inv),
                     f2bf(oa[4 * g + 2] * inv), f2bf(oa[4 * g + 3] * inv)};
            *(s4v*)(orow + d0) = p;
        }
    }
}

}  // namespace

extern "C" void kernel_launch(void* const* d_in, const int* in_sizes, int n_in,
                              void* d_out, int out_size, void* d_ws,
                              size_t ws_size, hipStream_t stream) {
    const float* x   = (const float*)d_in[0];
    const float* ctx = (const float*)d_in[1];
    const float* Wq  = (const float*)d_in[2];
    const float* bq  = (const float*)d_in[3];
    const float* Wk  = (const float*)d_in[4];
    const float* bk  = (const float*)d_in[5];
    const float* Wv  = (const float*)d_in[6];
    const float* bv  = (const float*)d_in[7];
    const float* Wo  = (const float*)d_in[8];
    const float* bo  = (const float*)d_in[9];

    short* xb  = (short*)d_ws;            // [4096,1024]
    short* cb  = xb + (size_t)4096 * 1024;   // [4096,768]
    short* Wqt = cb + (size_t)4096 * 768;    // [1024,1024]
    short* Wkt = Wqt + (size_t)1024 * 1024;  // [1024,768]
    short* Wvt = Wkt + (size_t)1024 * 768;   // [1024,768]
    short* Wot = Wvt + (size_t)1024 * 768;   // [1024,1024]
    short* Qf  = Wot + (size_t)1024 * 1024;  // [4096,1024] (x0.125)
    short* Kf  = Qf + (size_t)4096 * 1024;   // [4096,1024]
    short* Vt  = Kf + (size_t)4096 * 1024;   // [2,16,64,2048]
    short* ao  = Vt + (size_t)4096 * 1024;   // [4096,1024]

    tobf<<<4096, 256, 0, stream>>>(x, xb, 1048576);
    tobf<<<3072, 256, 0, stream>>>(ctx, cb, 786432);
    wtrans<<<dim3(16, 16), 256, 0, stream>>>(Wq, Wqt, 1024, 1024);
    wtrans<<<dim3(16, 12), 256, 0, stream>>>(Wk, Wkt, 768, 1024);
    wtrans<<<dim3(16, 12), 256, 0, stream>>>(Wv, Wvt, 768, 1024);
    wtrans<<<dim3(16, 16), 256, 0, stream>>>(Wo, Wot, 1024, 1024);

    gemm_bf16<0><<<dim3(16, 32), 128, 0, stream>>>(xb, Wqt, bq, Qf, 1024, 0.125f);
    gemm_bf16<0><<<dim3(16, 32), 128, 0, stream>>>(cb, Wkt, bk, Kf, 768, 1.f);
    gemm_bf16<1><<<dim3(16, 32), 128, 0, stream>>>(cb, Wvt, bv, Vt, 768, 1.f);

    attn<<<512, 256, 0, stream>>>(Qf, Kf, Vt, ao);

    gemm_bf16<2><<<dim3(16, 32), 128, 0, stream>>>(ao, Wot, bo, d_out, 1024, 1.f);
}

// Round 3
// 340.354 us; speedup vs baseline: 3.2738x; 1.0651x over previous
//
#include <hip/hip_runtime.h>
#include <math.h>

// CrossAttention B=2,S=2048,E=1024,H=16,Dh=64,NC=768 — fp32 in/out.
// R3: (a) GEMMs -> m97-style LDS staging (global_load_lds w16, 128x128 tile,
//     BK=32, ds_read_b128 frags, 8x mfma_32x32x16_bf16 per wave-iter).
//     (b) attention: no-max softmax (scores bounded, exp2 with log2e folded
//     into Q prescale), KV-split x2 with unnormalized bf16 partials + l sums,
//     P packed to bf16 by v_perm truncation. (c) combine kernel merges splits.

namespace {

typedef short bfr __attribute__((ext_vector_type(8)));   // 8 bf16 = 4 VGPR
typedef short s4v __attribute__((ext_vector_type(4)));
typedef unsigned u4v __attribute__((ext_vector_type(4)));
typedef float accf __attribute__((ext_vector_type(16)));

#define MFMA32(a, b, c) __builtin_amdgcn_mfma_f32_32x32x16_bf16(a, b, c, 0, 0, 0)

__device__ inline short f2bf(float f) {  // RNE
    unsigned u = __float_as_uint(f);
    u += 0x7fffu + ((u >> 16) & 1u);
    return (short)(u >> 16);
}
__device__ inline float bf2f(short s) {
    return __uint_as_float(((unsigned)(unsigned short)s) << 16);
}
__device__ inline accf zero16() {
    accf z;
#pragma unroll
    for (int i = 0; i < 16; ++i) z[i] = 0.f;
    return z;
}
__device__ inline void dma16(const void* g, void* l) {
    __builtin_amdgcn_global_load_lds(
        (const __attribute__((address_space(1))) void*)g,
        (__attribute__((address_space(3))) void*)l, 16, 0, 0);
}

// ---------- prep ----------
__global__ __launch_bounds__(256) void tobf(const float* __restrict__ in,
                                            short* __restrict__ out, int n4) {
    int i = blockIdx.x * 256 + threadIdx.x;
    if (i < n4) {
        float4 v = ((const float4*)in)[i];
        s4v p = {f2bf(v.x), f2bf(v.y), f2bf(v.z), f2bf(v.w)};
        ((s4v*)out)[i] = p;
    }
}

__global__ __launch_bounds__(256) void wtrans(const float* __restrict__ W,
                                              short* __restrict__ Wt,
                                              int K, int N) {
    __shared__ short t[64][68];
    const int tid = threadIdx.x;
    const int k0 = blockIdx.y * 64, n0 = blockIdx.x * 64;
    const int kr = tid >> 4, nc = (tid & 15) * 4;
#pragma unroll
    for (int rep = 0; rep < 4; ++rep) {
        int k = kr + rep * 16;
        float4 v = *(const float4*)&W[(size_t)(k0 + k) * N + n0 + nc];
        t[nc + 0][k] = f2bf(v.x);
        t[nc + 1][k] = f2bf(v.y);
        t[nc + 2][k] = f2bf(v.z);
        t[nc + 3][k] = f2bf(v.w);
    }
    __syncthreads();
    const int nr = tid >> 4, kc = (tid & 15) * 4;
#pragma unroll
    for (int rep = 0; rep < 4; ++rep) {
        int n = nr + rep * 16;
        s4v p = {t[n][kc], t[n][kc + 1], t[n][kc + 2], t[n][kc + 3]};
        *(s4v*)&Wt[(size_t)(n0 + n) * K + k0 + kc] = p;
    }
}

// ---------- LDS-staged bf16 GEMM: C = A[M,K] @ Bt[N,K]^T (+bias)*scale -----
// Block 256 thr = 4 waves (2x2), tile 128x128, BK=32.
// MODE 0: bf16 out [M,1024]. MODE 1: V^T bf16 [B,H,64,S]. MODE 2: fp32 [M,1024].
template <int MODE>
__global__ __launch_bounds__(256) void gemm_lds(
    const short* __restrict__ A, const short* __restrict__ Bt,
    const float* __restrict__ bias, void* __restrict__ out,
    int K, float scale) {
    __shared__ short As[4096];  // [128 rows][32 k] row-major, 8 KB
    __shared__ short Bs[4096];
    const int t = threadIdx.x, lane = t & 63, w = t >> 6;
    const int lm = lane & 31, h2 = lane >> 5;
    const int wm = w & 1, wn = w >> 1;
    const int m0 = blockIdx.y * 128, n0 = blockIdx.x * 128;

    const int srow = t >> 2, scol = (t & 3) * 8;  // DMA: lds byte off = 16*t
    const short* ga = A + (size_t)(m0 + srow) * K + scol;
    const short* gb = Bt + (size_t)(n0 + srow) * K + scol;
    short* lA = As + w * 512;  // wave-uniform LDS base (lane*16B implicit)
    short* lB = Bs + w * 512;

    const int aoff = (wm * 64 + lm) * 32 + h2 * 8;
    const int boff = (wn * 64 + lm) * 32 + h2 * 8;

    accf acc[2][2] = {zero16(), zero16(), zero16(), zero16()};

    for (int kt = 0; kt < K; kt += 32) {
        __syncthreads();  // prev tile fully consumed
        dma16(ga + kt, lA);
        dma16(ga + (size_t)64 * K + kt, lA + 2048);
        dma16(gb + kt, lB);
        dma16(gb + (size_t)64 * K + kt, lB + 2048);
        __syncthreads();  // drains vmcnt (DMA) before reads
#pragma unroll
        for (int kk = 0; kk < 32; kk += 16) {
            bfr a0 = *(const bfr*)&As[aoff + kk];
            bfr a1 = *(const bfr*)&As[aoff + 1024 + kk];
            bfr b0 = *(const bfr*)&Bs[boff + kk];
            bfr b1 = *(const bfr*)&Bs[boff + 1024 + kk];
            acc[0][0] = MFMA32(a0, b0, acc[0][0]);
            acc[0][1] = MFMA32(a0, b1, acc[0][1]);
            acc[1][0] = MFMA32(a1, b0, acc[1][0]);
            acc[1][1] = MFMA32(a1, b1, acc[1][1]);
        }
    }

#pragma unroll
    for (int nt = 0; nt < 2; ++nt) {
        const int n = n0 + wn * 64 + nt * 32 + lm;
        const float bn = bias[n];
#pragma unroll
        for (int mt = 0; mt < 2; ++mt) {
            const int mbase = m0 + wm * 64 + mt * 32 + 4 * h2;
            if (MODE == 1) {
                const int h = n >> 6, d = n & 63;
#pragma unroll
                for (int g = 0; g < 4; ++g) {
                    const int m = mbase + 8 * g;
                    const int bb = m >> 11, s = m & 2047;
                    s4v p = {f2bf((acc[mt][nt][4 * g + 0] + bn) * scale),
                             f2bf((acc[mt][nt][4 * g + 1] + bn) * scale),
                             f2bf((acc[mt][nt][4 * g + 2] + bn) * scale),
                             f2bf((acc[mt][nt][4 * g + 3] + bn) * scale)};
                    *(s4v*)((short*)out +
                            ((size_t)((bb * 16 + h) * 64 + d)) * 2048 + s) = p;
                }
            } else {
#pragma unroll
                for (int r = 0; r < 16; ++r) {
                    const int m = mbase + (r & 3) + 8 * (r >> 2);
                    float v = (acc[mt][nt][r] + bn) * scale;
                    if (MODE == 0)
                        ((short*)out)[(size_t)m * 1024 + n] = f2bf(v);
                    else
                        ((float*)out)[(size_t)m * 1024 + n] = v;
                }
            }
        }
    }
}

// ---------- flash attention, no-max softmax, KV-split x2 ----------
// Qf pre-scaled by 0.125*log2(e); P = exp2(S'). Partials unnormalized.
// bid = ((qb*2+split)<<5) | (b*16+h); 1024 blocks, 4 waves, 32 q-rows/wave.
__global__ __launch_bounds__(256, 3) void attn(
    const short* __restrict__ Qf, const short* __restrict__ Kf,
    const short* __restrict__ Vt, short* __restrict__ part,
    float* __restrict__ lsum) {
    const int bid = blockIdx.x;
    const int hidx = bid & 31, qs = bid >> 5;
    const int split = qs & 1, qb = qs >> 1;
    const int b = hidx >> 4, h = hidx & 15;
    const int lane = threadIdx.x & 63, wv = threadIdx.x >> 6;
    const int lm = lane & 31, h2 = lane >> 5;
    const bool hb = h2 != 0;
    const int q0 = qb * 128 + wv * 32;
    const int kv0 = split * 1024;

    const short* qp = Qf + (size_t)(b * 2048 + q0 + lm) * 1024 + h * 64 + h2 * 8;
    bfr qf[4];
#pragma unroll
    for (int kc = 0; kc < 4; ++kc) qf[kc] = *(const bfr*)(qp + kc * 16);

    const short* kb = Kf + ((size_t)(b * 2048 + kv0)) * 1024 + h * 64 + h2 * 8;
    const short* vb = Vt + ((size_t)(hidx * 64 + lm)) * 2048 + kv0 + h2 * 8;

    accf oa0 = zero16(), oa1 = zero16();  // O^T[d][q], unnormalized
    float la0 = 0.f, la1 = 0.f, la2 = 0.f, la3 = 0.f;

#pragma unroll 1
    for (int kt = 0; kt < 1024; kt += 64) {
        // K A-frags
        bfr kf0[4], kf1[4];
        const short* k0p = kb + (size_t)(kt + lm) * 1024;
        const short* k1p = k0p + (size_t)32 * 1024;
#pragma unroll
        for (int kc = 0; kc < 4; ++kc) {
            kf0[kc] = *(const bfr*)(k0p + kc * 16);
            kf1[kc] = *(const bfr*)(k1p + kc * 16);
        }
        accf s0 = zero16(), s1 = zero16();
#pragma unroll
        for (int kc = 0; kc < 4; ++kc) {
            s0 = MFMA32(kf0[kc], qf[kc], s0);
            s1 = MFMA32(kf1[kc], qf[kc], s1);
        }
        // V^T A-frags (kf regs recycle into vf; loads overlap softmax VALU)
        bfr vf0[4], vf1[4];
#pragma unroll
        for (int kc = 0; kc < 4; ++kc) {
            vf0[kc] = *(const bfr*)(vb + kt + kc * 16);
            vf1[kc] = *(const bfr*)(vb + (size_t)32 * 2048 + kt + kc * 16);
        }

        // P = exp2(S'); accumulate l in 4 independent partials
#pragma unroll
        for (int i = 0; i < 16; ++i) s0[i] = exp2f(s0[i]);
#pragma unroll
        for (int i = 0; i < 16; ++i) s1[i] = exp2f(s1[i]);
#pragma unroll
        for (int i = 0; i < 16; ++i) {
            if ((i & 3) == 0) la0 += s0[i] + s1[i];
            else if ((i & 3) == 1) la1 += s0[i] + s1[i];
            else if ((i & 3) == 2) la2 += s0[i] + s1[i];
            else la3 += s0[i] + s1[i];
        }

        // transpose C-layout -> B-frags; pack bf16 by truncation (v_perm)
        bfr pb[4];
#pragma unroll
        for (int kc = 0; kc < 4; ++kc) {
            const int base = 8 * (kc & 1);
            float e[8];
#pragma unroll
            for (int i = 0; i < 4; ++i) {
                float lo = (kc < 2) ? s0[base + i] : s1[base + i];
                float hi = (kc < 2) ? s0[base + 4 + i] : s1[base + 4 + i];
                float own = hb ? hi : lo;
                float con = hb ? lo : hi;
                float rcv = __shfl_xor(con, 32);
                e[i]     = hb ? rcv : own;
                e[4 + i] = hb ? own : rcv;
            }
            u4v pw;
#pragma unroll
            for (int j = 0; j < 4; ++j)
                pw[j] = __builtin_amdgcn_perm(__float_as_uint(e[2 * j + 1]),
                                              __float_as_uint(e[2 * j]),
                                              0x07060302u);
            pb[kc] = __builtin_bit_cast(bfr, pw);
        }

        // O^T += V^T @ P^T
#pragma unroll
        for (int kc = 0; kc < 4; ++kc) {
            oa0 = MFMA32(vf0[kc], pb[kc], oa0);
            oa1 = MFMA32(vf1[kc], pb[kc], oa1);
        }
    }

    float ls = la0 + la1 + la2 + la3;
    ls += __shfl_xor(ls, 32);
    if (!hb) lsum[((size_t)(split * 2 + b) * 16 + h) * 2048 + q0 + lm] = ls;

    short* orow = part + (size_t)split * 4096 * 1024 +
                  (size_t)(b * 2048 + q0 + lm) * 1024 + h * 64;
#pragma unroll
    for (int dt = 0; dt < 2; ++dt) {
        const accf& oa = dt ? oa1 : oa0;
#pragma unroll
        for (int g = 0; g < 4; ++g) {
            const int d0 = dt * 32 + 4 * h2 + 8 * g;
            s4v p = {f2bf(oa[4 * g + 0]), f2bf(oa[4 * g + 1]),
                     f2bf(oa[4 * g + 2]), f2bf(oa[4 * g + 3])};
            *(s4v*)(orow + d0) = p;
        }
    }
}

// ---------- combine splits: ao = (P0 + P1) / (l0 + l1) ----------
__global__ __launch_bounds__(256) void combine(
    const short* __restrict__ p0, const short* __restrict__ p1,
    const float* __restrict__ lsum, short* __restrict__ ao) {
    const int t = blockIdx.x * 256 + threadIdx.x;  // 524288 threads x 8 elems
    const int col8 = t & 127, m = t >> 7;
    const int h = col8 >> 3;
    const int b = m >> 11, q = m & 2047;
    const float l0 = lsum[((size_t)(0 + b) * 16 + h) * 2048 + q];
    const float l1 = lsum[((size_t)(2 + b) * 16 + h) * 2048 + q];
    const float inv = 1.f / (l0 + l1);
    const size_t e0 = (size_t)m * 1024 + col8 * 8;
    bfr a = *(const bfr*)(p0 + e0);
    bfr c = *(const bfr*)(p1 + e0);
    bfr r;
#pragma unroll
    for (int j = 0; j < 8; ++j) r[j] = f2bf((bf2f(a[j]) + bf2f(c[j])) * inv);
    *(bfr*)(ao + e0) = r;
}

}  // namespace

extern "C" void kernel_launch(void* const* d_in, const int* in_sizes, int n_in,
                              void* d_out, int out_size, void* d_ws,
                              size_t ws_size, hipStream_t stream) {
    const float* x   = (const float*)d_in[0];
    const float* ctx = (const float*)d_in[1];
    const float* Wq  = (const float*)d_in[2];
    const float* bq  = (const float*)d_in[3];
    const float* Wk  = (const float*)d_in[4];
    const float* bk  = (const float*)d_in[5];
    const float* Wv  = (const float*)d_in[6];
    const float* bv  = (const float*)d_in[7];
    const float* Wo  = (const float*)d_in[8];
    const float* bo  = (const float*)d_in[9];

    short* xb  = (short*)d_ws;               // [4096,1024] -> later reused as ao
    short* cb  = xb + (size_t)4096 * 1024;
    short* Wqt = cb + (size_t)4096 * 768;
    short* Wkt = Wqt + (size_t)1024 * 1024;
    short* Wvt = Wkt + (size_t)1024 * 768;
    short* Wot = Wvt + (size_t)1024 * 768;
    short* Qf  = Wot + (size_t)1024 * 1024;  // pre-scaled by 0.125*log2(e)
    short* Kf  = Qf + (size_t)4096 * 1024;
    short* Vt  = Kf + (size_t)4096 * 1024;   // [2,16,64,2048]
    short* p0  = Vt + (size_t)4096 * 1024;   // split partials (unnormalized)
    short* p1  = p0 + (size_t)4096 * 1024;
    float* lsum = (float*)(p1 + (size_t)4096 * 1024);  // [2][2][16][2048]

    tobf<<<4096, 256, 0, stream>>>(x, xb, 1048576);
    tobf<<<3072, 256, 0, stream>>>(ctx, cb, 786432);
    wtrans<<<dim3(16, 16), 256, 0, stream>>>(Wq, Wqt, 1024, 1024);
    wtrans<<<dim3(16, 12), 256, 0, stream>>>(Wk, Wkt, 768, 1024);
    wtrans<<<dim3(16, 12), 256, 0, stream>>>(Wv, Wvt, 768, 1024);
    wtrans<<<dim3(16, 16), 256, 0, stream>>>(Wo, Wot, 1024, 1024);

    const float qscale = 0.125f * 1.44269504088896f;
    gemm_lds<0><<<dim3(8, 32), 256, 0, stream>>>(xb, Wqt, bq, Qf, 1024, qscale);
    gemm_lds<0><<<dim3(8, 32), 256, 0, stream>>>(cb, Wkt, bk, Kf, 768, 1.f);
    gemm_lds<1><<<dim3(8, 32), 256, 0, stream>>>(cb, Wvt, bv, Vt, 768, 1.f);

    attn<<<1024, 256, 0, stream>>>(Qf, Kf, Vt, p0, lsum);
    combine<<<2048, 256, 0, stream>>>(p0, p1, lsum, xb);  // xb becomes ao

    gemm_lds<2><<<dim3(8, 32), 256, 0, stream>>>(xb, Wot, bo, d_out, 1024, 1.f);
}

// Round 4
// 262.949 us; speedup vs baseline: 4.2375x; 1.2944x over previous
//
#include <hip/hip_runtime.h>
#include <math.h>

// CrossAttention B=2,S=2048,E=1024,H=16,Dh=64,NC=768 — fp32 in/out.
// R4: attention Q/K/V stored in MFMA-fragment order (per head, per 32-row
// block: 4KB chunk, frag kc at base+kc*512+lane*8) so every attention frag
// load is one coalesced 1KB global_load_dwordx4 (R3 was 2KB-strided, TA-bound:
// 60% idle cycles). exp2 via __builtin_amdgcn_exp2f (single v_exp_f32).
// Prep launches merged. GEMMs keep R3 m97-style LDS staging; epilogues write
// the frag-order layouts.

namespace {

typedef short bfr __attribute__((ext_vector_type(8)));   // 8 bf16 = 4 VGPR
typedef short s4v __attribute__((ext_vector_type(4)));
typedef unsigned u4v __attribute__((ext_vector_type(4)));
typedef float accf __attribute__((ext_vector_type(16)));

#define MFMA32(a, b, c) __builtin_amdgcn_mfma_f32_32x32x16_bf16(a, b, c, 0, 0, 0)

__device__ inline short f2bf(float f) {  // RNE
    unsigned u = __float_as_uint(f);
    u += 0x7fffu + ((u >> 16) & 1u);
    return (short)(u >> 16);
}
__device__ inline float bf2f(short s) {
    return __uint_as_float(((unsigned)(unsigned short)s) << 16);
}
__device__ inline float fexp2(float x) { return __builtin_amdgcn_exp2f(x); }
__device__ inline accf zero16() {
    accf z;
#pragma unroll
    for (int i = 0; i < 16; ++i) z[i] = 0.f;
    return z;
}
__device__ inline void dma16(const void* g, void* l) {
    __builtin_amdgcn_global_load_lds(
        (const __attribute__((address_space(1))) void*)g,
        (__attribute__((address_space(3))) void*)l, 16, 0, 0);
}

// ---------- prep: x & ctx fp32 -> bf16, one launch ----------
__global__ __launch_bounds__(256) void tobf2(const float* __restrict__ x,
                                             const float* __restrict__ c,
                                             short* __restrict__ xb,
                                             short* __restrict__ cb) {
    int i = blockIdx.x * 256 + threadIdx.x;
    if (i < 1048576) {
        float4 v = ((const float4*)x)[i];
        s4v p = {f2bf(v.x), f2bf(v.y), f2bf(v.z), f2bf(v.w)};
        ((s4v*)xb)[i] = p;
    } else {
        int j = i - 1048576;
        float4 v = ((const float4*)c)[j];
        s4v p = {f2bf(v.x), f2bf(v.y), f2bf(v.z), f2bf(v.w)};
        ((s4v*)cb)[j] = p;
    }
}

// ---------- prep: all 4 weight transposes, one launch (z selects) ----------
__global__ __launch_bounds__(256) void wtrans4(
    const float* __restrict__ Wq, const float* __restrict__ Wk,
    const float* __restrict__ Wv, const float* __restrict__ Wo,
    short* __restrict__ Wqt, short* __restrict__ Wkt,
    short* __restrict__ Wvt, short* __restrict__ Wot) {
    const float* W;
    short* Wt;
    int K;
    switch (blockIdx.z) {
        case 0: W = Wq; Wt = Wqt; K = 1024; break;
        case 1: W = Wk; Wt = Wkt; K = 768; break;
        case 2: W = Wv; Wt = Wvt; K = 768; break;
        default: W = Wo; Wt = Wot; K = 1024; break;
    }
    const int k0 = blockIdx.y * 64;
    if (k0 >= K) return;
    __shared__ short t[64][68];
    const int tid = threadIdx.x;
    const int n0 = blockIdx.x * 64;
    const int kr = tid >> 4, nc = (tid & 15) * 4;
#pragma unroll
    for (int rep = 0; rep < 4; ++rep) {
        int k = kr + rep * 16;
        float4 v = *(const float4*)&W[(size_t)(k0 + k) * 1024 + n0 + nc];
        t[nc + 0][k] = f2bf(v.x);
        t[nc + 1][k] = f2bf(v.y);
        t[nc + 2][k] = f2bf(v.z);
        t[nc + 3][k] = f2bf(v.w);
    }
    __syncthreads();
    const int nr = tid >> 4, kc = (tid & 15) * 4;
#pragma unroll
    for (int rep = 0; rep < 4; ++rep) {
        int n = nr + rep * 16;
        s4v p = {t[n][kc], t[n][kc + 1], t[n][kc + 2], t[n][kc + 3]};
        *(s4v*)&Wt[(size_t)(n0 + n) * K + k0 + kc] = p;
    }
}

// ---------- LDS-staged bf16 GEMM: C = A[M,K] @ Bt[N=1024,K]^T (+bias)*scale
// Block 256 = 4 waves (2x2), tile 128x128, BK=32, global_load_lds w16.
// MODE 2: fp32 row-major [M,1024].
// MODE 3: frag-order QK bf16: chunk(b,h,row32)=4KB, off kc*512+h2*256+lm*8+j.
// MODE 4: frag-order V bf16: chunk(b,h,kvt64,dblk)=4KB (V^T fragments).
template <int MODE>
__global__ __launch_bounds__(256) void gemm_lds(
    const short* __restrict__ A, const short* __restrict__ Bt,
    const float* __restrict__ bias, void* __restrict__ out,
    int K, float scale) {
    __shared__ short As[4096];  // [128 rows][32 k] row-major, 8 KB
    __shared__ short Bs[4096];
    const int t = threadIdx.x, lane = t & 63, w = t >> 6;
    const int lm = lane & 31, h2 = lane >> 5;
    const int wm = w & 1, wn = w >> 1;
    const int m0 = blockIdx.y * 128, n0 = blockIdx.x * 128;

    const int srow = t >> 2, scol = (t & 3) * 8;
    const short* ga = A + (size_t)(m0 + srow) * K + scol;
    const short* gb = Bt + (size_t)(n0 + srow) * K + scol;
    short* lA = As + w * 512;
    short* lB = Bs + w * 512;

    const int aoff = (wm * 64 + lm) * 32 + h2 * 8;
    const int boff = (wn * 64 + lm) * 32 + h2 * 8;

    accf acc[2][2] = {zero16(), zero16(), zero16(), zero16()};

    for (int kt = 0; kt < K; kt += 32) {
        __syncthreads();
        dma16(ga + kt, lA);
        dma16(ga + (size_t)64 * K + kt, lA + 2048);
        dma16(gb + kt, lB);
        dma16(gb + (size_t)64 * K + kt, lB + 2048);
        __syncthreads();
#pragma unroll
        for (int kk = 0; kk < 32; kk += 16) {
            bfr a0 = *(const bfr*)&As[aoff + kk];
            bfr a1 = *(const bfr*)&As[aoff + 1024 + kk];
            bfr b0 = *(const bfr*)&Bs[boff + kk];
            bfr b1 = *(const bfr*)&Bs[boff + 1024 + kk];
            acc[0][0] = MFMA32(a0, b0, acc[0][0]);
            acc[0][1] = MFMA32(a0, b1, acc[0][1]);
            acc[1][0] = MFMA32(a1, b0, acc[1][0]);
            acc[1][1] = MFMA32(a1, b1, acc[1][1]);
        }
    }

#pragma unroll
    for (int nt = 0; nt < 2; ++nt) {
        const int n = n0 + wn * 64 + nt * 32 + lm;
        const float bn = bias[n];
#pragma unroll
        for (int mt = 0; mt < 2; ++mt) {
            const int mbase = m0 + wm * 64 + mt * 32 + 4 * h2;
            if (MODE == 3) {
                const int hh = n >> 6, dd = n & 63;
                const int cb2 = (dd >> 4) * 512 + ((dd >> 3) & 1) * 256 + (dd & 7);
#pragma unroll
                for (int r = 0; r < 16; ++r) {
                    const int m = mbase + (r & 3) + 8 * (r >> 2);
                    const int bb = m >> 11, q = m & 2047;
                    float v = (acc[mt][nt][r] + bn) * scale;
                    ((short*)out)[((size_t)((bb * 16 + hh) * 64 + (q >> 5))) * 2048 +
                                  cb2 + (q & 31) * 8] = f2bf(v);
                }
            } else if (MODE == 4) {
                const int hh = n >> 6, dd = n & 63;
                const int dblk = dd >> 5, lmv = dd & 31;
#pragma unroll
                for (int g = 0; g < 4; ++g) {
                    const int m = mbase + 8 * g;
                    const int bb = m >> 11, s = m & 2047;
                    const int kvt = s >> 6, kc = (s >> 4) & 3;
                    const int h2v = (s >> 3) & 1, j0 = s & 7;
                    s4v p = {f2bf((acc[mt][nt][4 * g + 0] + bn) * scale),
                             f2bf((acc[mt][nt][4 * g + 1] + bn) * scale),
                             f2bf((acc[mt][nt][4 * g + 2] + bn) * scale),
                             f2bf((acc[mt][nt][4 * g + 3] + bn) * scale)};
                    *(s4v*)((short*)out +
                            ((size_t)(((bb * 16 + hh) * 32 + kvt) * 2 + dblk)) * 2048 +
                            kc * 512 + h2v * 256 + lmv * 8 + j0) = p;
                }
            } else {
#pragma unroll
                for (int r = 0; r < 16; ++r) {
                    const int m = mbase + (r & 3) + 8 * (r >> 2);
                    float v = (acc[mt][nt][r] + bn) * scale;
                    ((float*)out)[(size_t)m * 1024 + n] = v;
                }
            }
        }
    }
}

// ---------- flash attention, no-max softmax, KV-split x2, frag-order IO ----
// Qf/Kf: chunk(hidx, row32) 2048 elems; Vt: chunk(hidx, kvt64, dblk) 2048.
// All frag loads: base + kc*512 + lane*8 — coalesced 1KB per instruction.
__global__ __launch_bounds__(256, 4) void attn(
    const short* __restrict__ Qf, const short* __restrict__ Kf,
    const short* __restrict__ Vt, short* __restrict__ part,
    float* __restrict__ lsum) {
    const int bid = blockIdx.x;
    const int hidx = bid & 31, qs = bid >> 5;
    const int split = qs & 1, qb = qs >> 1;
    const int b = hidx >> 4, h = hidx & 15;
    const int lane = threadIdx.x & 63, wv = threadIdx.x >> 6;
    const int lm = lane & 31, h2 = lane >> 5;
    const bool hb = h2 != 0;
    const int q0 = qb * 128 + wv * 32;
    const int kv0 = split * 1024;

    const short* qbase =
        Qf + ((size_t)(hidx * 64 + (q0 >> 5))) * 2048 + lane * 8;
    bfr qf[4];
#pragma unroll
    for (int kc = 0; kc < 4; ++kc) qf[kc] = *(const bfr*)(qbase + kc * 512);

    const short* kbase =
        Kf + ((size_t)(hidx * 64 + (kv0 >> 5))) * 2048 + lane * 8;
    const short* vbase =
        Vt + ((size_t)(hidx * 32 + (kv0 >> 6))) * 4096 + lane * 8;

    accf oa0 = zero16(), oa1 = zero16();  // O^T[d][q], unnormalized
    float la0 = 0.f, la1 = 0.f, la2 = 0.f, la3 = 0.f;

#pragma unroll 1
    for (int kt = 0; kt < 1024; kt += 64) {
        const short* kp = kbase + (size_t)(kt >> 5) * 2048;
        bfr kf0[4], kf1[4];
#pragma unroll
        for (int kc = 0; kc < 4; ++kc) {
            kf0[kc] = *(const bfr*)(kp + kc * 512);
            kf1[kc] = *(const bfr*)(kp + 2048 + kc * 512);
        }
        accf s0 = zero16(), s1 = zero16();
#pragma unroll
        for (int kc = 0; kc < 4; ++kc) {
            s0 = MFMA32(kf0[kc], qf[kc], s0);
            s1 = MFMA32(kf1[kc], qf[kc], s1);
        }
        const short* vp = vbase + (size_t)(kt >> 6) * 4096;
        bfr vf0[4], vf1[4];
#pragma unroll
        for (int kc = 0; kc < 4; ++kc) {
            vf0[kc] = *(const bfr*)(vp + kc * 512);
            vf1[kc] = *(const bfr*)(vp + 2048 + kc * 512);
        }

        // P = exp2(S'); accumulate l in 4 independent partials
#pragma unroll
        for (int i = 0; i < 16; ++i) s0[i] = fexp2(s0[i]);
#pragma unroll
        for (int i = 0; i < 16; ++i) s1[i] = fexp2(s1[i]);
#pragma unroll
        for (int i = 0; i < 16; ++i) {
            if ((i & 3) == 0) la0 += s0[i] + s1[i];
            else if ((i & 3) == 1) la1 += s0[i] + s1[i];
            else if ((i & 3) == 2) la2 += s0[i] + s1[i];
            else la3 += s0[i] + s1[i];
        }

        // transpose C-layout -> B-frags; bf16 by truncation (v_perm)
        bfr pb[4];
#pragma unroll
        for (int kc = 0; kc < 4; ++kc) {
            const int base = 8 * (kc & 1);
            float e[8];
#pragma unroll
            for (int i = 0; i < 4; ++i) {
                float lo = (kc < 2) ? s0[base + i] : s1[base + i];
                float hi = (kc < 2) ? s0[base + 4 + i] : s1[base + 4 + i];
                float own = hb ? hi : lo;
                float con = hb ? lo : hi;
                float rcv = __shfl_xor(con, 32);
                e[i]     = hb ? rcv : own;
                e[4 + i] = hb ? own : rcv;
            }
            u4v pw;
#pragma unroll
            for (int j = 0; j < 4; ++j)
                pw[j] = __builtin_amdgcn_perm(__float_as_uint(e[2 * j + 1]),
                                              __float_as_uint(e[2 * j]),
                                              0x07060302u);
            pb[kc] = __builtin_bit_cast(bfr, pw);
        }

        // O^T += V^T @ P^T
#pragma unroll
        for (int kc = 0; kc < 4; ++kc) {
            oa0 = MFMA32(vf0[kc], pb[kc], oa0);
            oa1 = MFMA32(vf1[kc], pb[kc], oa1);
        }
    }

    float ls = la0 + la1 + la2 + la3;
    ls += __shfl_xor(ls, 32);
    if (!hb) lsum[((size_t)(split * 2 + b) * 16 + h) * 2048 + q0 + lm] = ls;

    short* orow = part + (size_t)split * 4096 * 1024 +
                  (size_t)(b * 2048 + q0 + lm) * 1024 + h * 64;
#pragma unroll
    for (int dt = 0; dt < 2; ++dt) {
        const accf& oa = dt ? oa1 : oa0;
#pragma unroll
        for (int g = 0; g < 4; ++g) {
            const int d0 = dt * 32 + 4 * h2 + 8 * g;
            s4v p = {f2bf(oa[4 * g + 0]), f2bf(oa[4 * g + 1]),
                     f2bf(oa[4 * g + 2]), f2bf(oa[4 * g + 3])};
            *(s4v*)(orow + d0) = p;
        }
    }
}

// ---------- combine splits: ao = (P0 + P1) / (l0 + l1) ----------
__global__ __launch_bounds__(256) void combine(
    const short* __restrict__ p0, const short* __restrict__ p1,
    const float* __restrict__ lsum, short* __restrict__ ao) {
    const int t = blockIdx.x * 256 + threadIdx.x;
    const int col8 = t & 127, m = t >> 7;
    const int h = col8 >> 3;
    const int b = m >> 11, q = m & 2047;
    const float l0 = lsum[((size_t)(0 + b) * 16 + h) * 2048 + q];
    const float l1 = lsum[((size_t)(2 + b) * 16 + h) * 2048 + q];
    const float inv = 1.f / (l0 + l1);
    const size_t e0 = (size_t)m * 1024 + col8 * 8;
    bfr a = *(const bfr*)(p0 + e0);
    bfr c = *(const bfr*)(p1 + e0);
    bfr r;
#pragma unroll
    for (int j = 0; j < 8; ++j) r[j] = f2bf((bf2f(a[j]) + bf2f(c[j])) * inv);
    *(bfr*)(ao + e0) = r;
}

}  // namespace

extern "C" void kernel_launch(void* const* d_in, const int* in_sizes, int n_in,
                              void* d_out, int out_size, void* d_ws,
                              size_t ws_size, hipStream_t stream) {
    const float* x   = (const float*)d_in[0];
    const float* ctx = (const float*)d_in[1];
    const float* Wq  = (const float*)d_in[2];
    const float* bq  = (const float*)d_in[3];
    const float* Wk  = (const float*)d_in[4];
    const float* bk  = (const float*)d_in[5];
    const float* Wv  = (const float*)d_in[6];
    const float* bv  = (const float*)d_in[7];
    const float* Wo  = (const float*)d_in[8];
    const float* bo  = (const float*)d_in[9];

    short* xb  = (short*)d_ws;               // [4096,1024]; reused as ao later
    short* cb  = xb + (size_t)4096 * 1024;
    short* Wqt = cb + (size_t)4096 * 768;
    short* Wkt = Wqt + (size_t)1024 * 1024;
    short* Wvt = Wkt + (size_t)1024 * 768;
    short* Wot = Wvt + (size_t)1024 * 768;
    short* Qf  = Wot + (size_t)1024 * 1024;  // frag-order, pre-scaled
    short* Kf  = Qf + (size_t)4096 * 1024;   // frag-order
    short* Vt  = Kf + (size_t)4096 * 1024;   // frag-order V^T
    short* p0  = Vt + (size_t)4096 * 1024;   // split partials
    short* p1  = p0 + (size_t)4096 * 1024;
    float* lsum = (float*)(p1 + (size_t)4096 * 1024);  // [2][2][16][2048]

    tobf2<<<7168, 256, 0, stream>>>(x, ctx, xb, cb);
    wtrans4<<<dim3(16, 16, 4), 256, 0, stream>>>(Wq, Wk, Wv, Wo,
                                                 Wqt, Wkt, Wvt, Wot);

    const float qscale = 0.125f * 1.44269504088896f;
    gemm_lds<3><<<dim3(8, 32), 256, 0, stream>>>(xb, Wqt, bq, Qf, 1024, qscale);
    gemm_lds<3><<<dim3(8, 32), 256, 0, stream>>>(cb, Wkt, bk, Kf, 768, 1.f);
    gemm_lds<4><<<dim3(8, 32), 256, 0, stream>>>(cb, Wvt, bv, Vt, 768, 1.f);

    attn<<<1024, 256, 0, stream>>>(Qf, Kf, Vt, p0, lsum);
    combine<<<2048, 256, 0, stream>>>(p0, p1, lsum, xb);  // xb becomes ao

    gemm_lds<2><<<dim3(8, 32), 256, 0, stream>>>(xb, Wot, bo, d_out, 1024, 1.f);
}

// Round 5
// 227.223 us; speedup vs baseline: 4.9038x; 1.1572x over previous
//
#include <hip/hip_runtime.h>
#include <math.h>

// CrossAttention B=2,S=2048,E=1024,H=16,Dh=64,NC=768 — fp32 in/out.
// R5: (a) attn: K/V LDS-staged once per block (R4 bottleneck was 4x-redundant
// per-wave global frag loads, ~1.07 GB through L2), double-buffered, one
// barrier per iter; KV-split dropped; normalization in-kernel; combine kernel
// removed. (b) Q/K/V projection GEMMs fused into one 768-block dispatch.
// Layouts: Q/K/V in MFMA-frag order (4KB chunks, frag kc at kc*512+lane*8
// shorts) so DMA staging and ds_read_b128 fragment reads are both trivial.

namespace {

typedef short bfr __attribute__((ext_vector_type(8)));   // 8 bf16 = 4 VGPR
typedef short s4v __attribute__((ext_vector_type(4)));
typedef unsigned u4v __attribute__((ext_vector_type(4)));
typedef float accf __attribute__((ext_vector_type(16)));

#define MFMA32(a, b, c) __builtin_amdgcn_mfma_f32_32x32x16_bf16(a, b, c, 0, 0, 0)

__device__ inline short f2bf(float f) {  // RNE
    unsigned u = __float_as_uint(f);
    u += 0x7fffu + ((u >> 16) & 1u);
    return (short)(u >> 16);
}
__device__ inline float fexp2(float x) { return __builtin_amdgcn_exp2f(x); }
__device__ inline accf zero16() {
    accf z;
#pragma unroll
    for (int i = 0; i < 16; ++i) z[i] = 0.f;
    return z;
}
__device__ inline void dma16(const void* g, void* l) {
    __builtin_amdgcn_global_load_lds(
        (const __attribute__((address_space(1))) void*)g,
        (__attribute__((address_space(3))) void*)l, 16, 0, 0);
}

// ---------- prep: x & ctx fp32 -> bf16, one launch ----------
__global__ __launch_bounds__(256) void tobf2(const float* __restrict__ x,
                                             const float* __restrict__ c,
                                             short* __restrict__ xb,
                                             short* __restrict__ cb) {
    int i = blockIdx.x * 256 + threadIdx.x;
    if (i < 1048576) {
        float4 v = ((const float4*)x)[i];
        s4v p = {f2bf(v.x), f2bf(v.y), f2bf(v.z), f2bf(v.w)};
        ((s4v*)xb)[i] = p;
    } else {
        int j = i - 1048576;
        float4 v = ((const float4*)c)[j];
        s4v p = {f2bf(v.x), f2bf(v.y), f2bf(v.z), f2bf(v.w)};
        ((s4v*)cb)[j] = p;
    }
}

// ---------- prep: all 4 weight transposes, one launch (z selects) ----------
__global__ __launch_bounds__(256) void wtrans4(
    const float* __restrict__ Wq, const float* __restrict__ Wk,
    const float* __restrict__ Wv, const float* __restrict__ Wo,
    short* __restrict__ Wqt, short* __restrict__ Wkt,
    short* __restrict__ Wvt, short* __restrict__ Wot) {
    const float* W;
    short* Wt;
    int K;
    switch (blockIdx.z) {
        case 0: W = Wq; Wt = Wqt; K = 1024; break;
        case 1: W = Wk; Wt = Wkt; K = 768; break;
        case 2: W = Wv; Wt = Wvt; K = 768; break;
        default: W = Wo; Wt = Wot; K = 1024; break;
    }
    const int k0 = blockIdx.y * 64;
    if (k0 >= K) return;
    __shared__ short t[64][68];
    const int tid = threadIdx.x;
    const int n0 = blockIdx.x * 64;
    const int kr = tid >> 4, nc = (tid & 15) * 4;
#pragma unroll
    for (int rep = 0; rep < 4; ++rep) {
        int k = kr + rep * 16;
        float4 v = *(const float4*)&W[(size_t)(k0 + k) * 1024 + n0 + nc];
        t[nc + 0][k] = f2bf(v.x);
        t[nc + 1][k] = f2bf(v.y);
        t[nc + 2][k] = f2bf(v.z);
        t[nc + 3][k] = f2bf(v.w);
    }
    __syncthreads();
    const int nr = tid >> 4, kc = (tid & 15) * 4;
#pragma unroll
    for (int rep = 0; rep < 4; ++rep) {
        int n = nr + rep * 16;
        s4v p = {t[n][kc], t[n][kc + 1], t[n][kc + 2], t[n][kc + 3]};
        *(s4v*)&Wt[(size_t)(n0 + n) * K + k0 + kc] = p;
    }
}

// ---------- fused Q/K/V projection GEMM, blockIdx.z selects ----------
__global__ __launch_bounds__(256) void gemm_qkv(
    const short* __restrict__ xb, const short* __restrict__ cb,
    const short* __restrict__ Wqt, const short* __restrict__ Wkt,
    const short* __restrict__ Wvt, const float* __restrict__ bq,
    const float* __restrict__ bk, const float* __restrict__ bv,
    short* __restrict__ Qf, short* __restrict__ Kf, short* __restrict__ Vt,
    float qscale) {
    const int z = blockIdx.z;
    const short* A  = (z == 0) ? xb : cb;
    const short* Bt = (z == 0) ? Wqt : ((z == 1) ? Wkt : Wvt);
    const float* bias = (z == 0) ? bq : ((z == 1) ? bk : bv);
    const int K = (z == 0) ? 1024 : 768;
    const float scale = (z == 0) ? qscale : 1.f;
    short* out = (z == 0) ? Qf : ((z == 1) ? Kf : Vt);

    __shared__ short As[4096];
    __shared__ short Bs[4096];
    const int t = threadIdx.x, lane = t & 63, w = t >> 6;
    const int lm = lane & 31, h2 = lane >> 5;
    const int wm = w & 1, wn = w >> 1;
    const int m0 = blockIdx.y * 128, n0 = blockIdx.x * 128;

    const int srow = t >> 2, scol = (t & 3) * 8;
    const short* ga = A + (size_t)(m0 + srow) * K + scol;
    const short* gb = Bt + (size_t)(n0 + srow) * K + scol;
    short* lA = As + w * 512;
    short* lB = Bs + w * 512;

    const int aoff = (wm * 64 + lm) * 32 + h2 * 8;
    const int boff = (wn * 64 + lm) * 32 + h2 * 8;

    accf acc[2][2] = {zero16(), zero16(), zero16(), zero16()};

    for (int kt = 0; kt < K; kt += 32) {
        __syncthreads();
        dma16(ga + kt, lA);
        dma16(ga + (size_t)64 * K + kt, lA + 2048);
        dma16(gb + kt, lB);
        dma16(gb + (size_t)64 * K + kt, lB + 2048);
        __syncthreads();
#pragma unroll
        for (int kk = 0; kk < 32; kk += 16) {
            bfr a0 = *(const bfr*)&As[aoff + kk];
            bfr a1 = *(const bfr*)&As[aoff + 1024 + kk];
            bfr b0 = *(const bfr*)&Bs[boff + kk];
            bfr b1 = *(const bfr*)&Bs[boff + 1024 + kk];
            acc[0][0] = MFMA32(a0, b0, acc[0][0]);
            acc[0][1] = MFMA32(a0, b1, acc[0][1]);
            acc[1][0] = MFMA32(a1, b0, acc[1][0]);
            acc[1][1] = MFMA32(a1, b1, acc[1][1]);
        }
    }

#pragma unroll
    for (int nt = 0; nt < 2; ++nt) {
        const int n = n0 + wn * 64 + nt * 32 + lm;
        const float bn = bias[n];
        const int hh = n >> 6, dd = n & 63;
#pragma unroll
        for (int mt = 0; mt < 2; ++mt) {
            const int mbase = m0 + wm * 64 + mt * 32 + 4 * h2;
            if (z != 2) {
                const int cb2 = (dd >> 4) * 512 + ((dd >> 3) & 1) * 256 + (dd & 7);
#pragma unroll
                for (int r = 0; r < 16; ++r) {
                    const int m = mbase + (r & 3) + 8 * (r >> 2);
                    const int bb = m >> 11, q = m & 2047;
                    float v = (acc[mt][nt][r] + bn) * scale;
                    out[((size_t)((bb * 16 + hh) * 64 + (q >> 5))) * 2048 +
                        cb2 + (q & 31) * 8] = f2bf(v);
                }
            } else {
                const int dblk = dd >> 5, lmv = dd & 31;
#pragma unroll
                for (int g = 0; g < 4; ++g) {
                    const int m = mbase + 8 * g;
                    const int bb = m >> 11, s = m & 2047;
                    const int kvt = s >> 6, kc = (s >> 4) & 3;
                    const int h2v = (s >> 3) & 1, j0 = s & 7;
                    s4v p = {f2bf(acc[mt][nt][4 * g + 0] + bn),
                             f2bf(acc[mt][nt][4 * g + 1] + bn),
                             f2bf(acc[mt][nt][4 * g + 2] + bn),
                             f2bf(acc[mt][nt][4 * g + 3] + bn)};
                    *(s4v*)(out +
                            ((size_t)(((bb * 16 + hh) * 32 + kvt) * 2 + dblk)) * 2048 +
                            kc * 512 + h2v * 256 + lmv * 8 + j0) = p;
                }
            }
        }
    }
}

// ---------- output GEMM: fp32 C = ao@Wot + bo ----------
__global__ __launch_bounds__(256) void gemm_out(
    const short* __restrict__ A, const short* __restrict__ Bt,
    const float* __restrict__ bias, float* __restrict__ out, int K) {
    __shared__ short As[4096];
    __shared__ short Bs[4096];
    const int t = threadIdx.x, lane = t & 63, w = t >> 6;
    const int lm = lane & 31, h2 = lane >> 5;
    const int wm = w & 1, wn = w >> 1;
    const int m0 = blockIdx.y * 128, n0 = blockIdx.x * 128;

    const int srow = t >> 2, scol = (t & 3) * 8;
    const short* ga = A + (size_t)(m0 + srow) * K + scol;
    const short* gb = Bt + (size_t)(n0 + srow) * K + scol;
    short* lA = As + w * 512;
    short* lB = Bs + w * 512;

    const int aoff = (wm * 64 + lm) * 32 + h2 * 8;
    const int boff = (wn * 64 + lm) * 32 + h2 * 8;

    accf acc[2][2] = {zero16(), zero16(), zero16(), zero16()};

    for (int kt = 0; kt < K; kt += 32) {
        __syncthreads();
        dma16(ga + kt, lA);
        dma16(ga + (size_t)64 * K + kt, lA + 2048);
        dma16(gb + kt, lB);
        dma16(gb + (size_t)64 * K + kt, lB + 2048);
        __syncthreads();
#pragma unroll
        for (int kk = 0; kk < 32; kk += 16) {
            bfr a0 = *(const bfr*)&As[aoff + kk];
            bfr a1 = *(const bfr*)&As[aoff + 1024 + kk];
            bfr b0 = *(const bfr*)&Bs[boff + kk];
            bfr b1 = *(const bfr*)&Bs[boff + 1024 + kk];
            acc[0][0] = MFMA32(a0, b0, acc[0][0]);
            acc[0][1] = MFMA32(a0, b1, acc[0][1]);
            acc[1][0] = MFMA32(a1, b0, acc[1][0]);
            acc[1][1] = MFMA32(a1, b1, acc[1][1]);
        }
    }

#pragma unroll
    for (int nt = 0; nt < 2; ++nt) {
        const int n = n0 + wn * 64 + nt * 32 + lm;
        const float bn = bias[n];
#pragma unroll
        for (int mt = 0; mt < 2; ++mt) {
            const int mbase = m0 + wm * 64 + mt * 32 + 4 * h2;
#pragma unroll
            for (int r = 0; r < 16; ++r) {
                const int m = mbase + (r & 3) + 8 * (r >> 2);
                out[(size_t)m * 1024 + n] = acc[mt][nt][r] + bn;
            }
        }
    }
}

// ---------- flash attention: LDS-staged K/V, double-buffered ----------
__global__ __launch_bounds__(256) void attn(
    const short* __restrict__ Qf, const short* __restrict__ Kf,
    const short* __restrict__ Vt, short* __restrict__ ao) {
    __shared__ short smem[16384];  // 2 bufs x (K 4096 + V 4096 shorts) = 32 KB
    const int bid = blockIdx.x;
    const int hidx = bid & 31, qb = bid >> 5;
    const int b = hidx >> 4, h = hidx & 15;
    const int lane = threadIdx.x & 63, wv = threadIdx.x >> 6;
    const int lm = lane & 31, h2 = lane >> 5;
    const bool hb = h2 != 0;
    const int q0 = qb * 128 + wv * 32;

    const short* qbase =
        Qf + ((size_t)(hidx * 64 + (q0 >> 5))) * 2048 + lane * 8;
    bfr qf[4];
#pragma unroll
    for (int kc = 0; kc < 4; ++kc) qf[kc] = *(const bfr*)(qbase + kc * 512);

    // wave w stages quarter w of each iter's 16 KB (K 8KB | V 8KB)
    const short* khead = Kf + (size_t)hidx * 131072;
    const short* vhead = Vt + (size_t)hidx * 131072;
    const short* gsrc =
        ((wv < 2) ? (khead + wv * 2048) : (vhead + (wv - 2) * 2048)) + lane * 8;

#pragma unroll
    for (int i = 0; i < 4; ++i)
        dma16(gsrc + i * 512, &smem[wv * 2048 + i * 512]);

    accf oa0 = zero16(), oa1 = zero16();
    float la0 = 0.f, la1 = 0.f, la2 = 0.f, la3 = 0.f;

#pragma unroll 1
    for (int it = 0; it < 32; ++it) {
        const int p = it & 1;
        __syncthreads();  // buf p DMA drained (vmcnt(0) before s_barrier)
        if (it + 1 < 32) {
            const short* gn = gsrc + (size_t)(it + 1) * 4096;
            short* ln = &smem[(1 - p) * 8192 + wv * 2048];
#pragma unroll
            for (int i = 0; i < 4; ++i) dma16(gn + i * 512, ln + i * 512);
        }
        const short* kb = &smem[p * 8192];
        bfr kf0[4], kf1[4], vf0[4], vf1[4];
#pragma unroll
        for (int kc = 0; kc < 4; ++kc) {
            kf0[kc] = *(const bfr*)&kb[kc * 512 + lane * 8];
            kf1[kc] = *(const bfr*)&kb[2048 + kc * 512 + lane * 8];
            vf0[kc] = *(const bfr*)&kb[4096 + kc * 512 + lane * 8];
            vf1[kc] = *(const bfr*)&kb[6144 + kc * 512 + lane * 8];
        }
        accf s0 = zero16(), s1 = zero16();
#pragma unroll
        for (int kc = 0; kc < 4; ++kc) {
            s0 = MFMA32(kf0[kc], qf[kc], s0);
            s1 = MFMA32(kf1[kc], qf[kc], s1);
        }

#pragma unroll
        for (int i = 0; i < 16; ++i) s0[i] = fexp2(s0[i]);
#pragma unroll
        for (int i = 0; i < 16; ++i) s1[i] = fexp2(s1[i]);
#pragma unroll
        for (int i = 0; i < 16; ++i) {
            if ((i & 3) == 0) la0 += s0[i] + s1[i];
            else if ((i & 3) == 1) la1 += s0[i] + s1[i];
            else if ((i & 3) == 2) la2 += s0[i] + s1[i];
            else la3 += s0[i] + s1[i];
        }

        bfr pb[4];
#pragma unroll
        for (int kc = 0; kc < 4; ++kc) {
            const int base = 8 * (kc & 1);
            float e[8];
#pragma unroll
            for (int i = 0; i < 4; ++i) {
                float lo = (kc < 2) ? s0[base + i] : s1[base + i];
                float hi = (kc < 2) ? s0[base + 4 + i] : s1[base + 4 + i];
                float own = hb ? hi : lo;
                float con = hb ? lo : hi;
                float rcv = __shfl_xor(con, 32);
                e[i]     = hb ? rcv : own;
                e[4 + i] = hb ? own : rcv;
            }
            u4v pw;
#pragma unroll
            for (int j = 0; j < 4; ++j)
                pw[j] = __builtin_amdgcn_perm(__float_as_uint(e[2 * j + 1]),
                                              __float_as_uint(e[2 * j]),
                                              0x07060302u);
            pb[kc] = __builtin_bit_cast(bfr, pw);
        }

#pragma unroll
        for (int kc = 0; kc < 4; ++kc) {
            oa0 = MFMA32(vf0[kc], pb[kc], oa0);
            oa1 = MFMA32(vf1[kc], pb[kc], oa1);
        }
    }

    float ls = la0 + la1 + la2 + la3;
    ls += __shfl_xor(ls, 32);
    const float inv = 1.f / ls;

    short* orow = ao + (size_t)(b * 2048 + q0 + lm) * 1024 + h * 64;
#pragma unroll
    for (int dt = 0; dt < 2; ++dt) {
        const accf& oa = dt ? oa1 : oa0;
#pragma unroll
        for (int g = 0; g < 4; ++g) {
            const int d0 = dt * 32 + 4 * h2 + 8 * g;
            s4v p = {f2bf(oa[4 * g + 0] * inv), f2bf(oa[4 * g + 1] * inv),
                     f2bf(oa[4 * g + 2] * inv), f2bf(oa[4 * g + 3] * inv)};
            *(s4v*)(orow + d0) = p;
        }
    }
}

}  // namespace

extern "C" void kernel_launch(void* const* d_in, const int* in_sizes, int n_in,
                              void* d_out, int out_size, void* d_ws,
                              size_t ws_size, hipStream_t stream) {
    const float* x   = (const float*)d_in[0];
    const float* ctx = (const float*)d_in[1];
    const float* Wq  = (const float*)d_in[2];
    const float* bq  = (const float*)d_in[3];
    const float* Wk  = (const float*)d_in[4];
    const float* bk  = (const float*)d_in[5];
    const float* Wv  = (const float*)d_in[6];
    const float* bv  = (const float*)d_in[7];
    const float* Wo  = (const float*)d_in[8];
    const float* bo  = (const float*)d_in[9];

    short* xb  = (short*)d_ws;               // [4096,1024]; reused as ao later
    short* cb  = xb + (size_t)4096 * 1024;
    short* Wqt = cb + (size_t)4096 * 768;
    short* Wkt = Wqt + (size_t)1024 * 1024;
    short* Wvt = Wkt + (size_t)1024 * 768;
    short* Wot = Wvt + (size_t)1024 * 768;
    short* Qf  = Wot + (size_t)1024 * 1024;  // frag-order, pre-scaled
    short* Kf  = Qf + (size_t)4096 * 1024;   // frag-order
    short* Vt  = Kf + (size_t)4096 * 1024;   // frag-order V^T

    tobf2<<<7168, 256, 0, stream>>>(x, ctx, xb, cb);
    wtrans4<<<dim3(16, 16, 4), 256, 0, stream>>>(Wq, Wk, Wv, Wo,
                                                 Wqt, Wkt, Wvt, Wot);

    const float qscale = 0.125f * 1.44269504088896f;
    gemm_qkv<<<dim3(8, 32, 3), 256, 0, stream>>>(xb, cb, Wqt, Wkt, Wvt,
                                                 bq, bk, bv, Qf, Kf, Vt,
                                                 qscale);

    attn<<<512, 256, 0, stream>>>(Qf, Kf, Vt, xb);  // xb becomes ao

    gemm_out<<<dim3(8, 32), 256, 0, stream>>>(xb, Wot, bo, (float*)d_out, 1024);
}

// Round 7
// 222.857 us; speedup vs baseline: 4.9999x; 1.0196x over previous
//
#include <hip/hip_runtime.h>
#include <math.h>

// CrossAttention B=2,S=2048,E=1024,H=16,Dh=64,NC=768 — fp32 in/out.
// R7 = R6 with the attn grid fixed: KV-split grid is 1024 blocks
// (16 qb x 2 splits x 32 hidx); R6 launched 2048 -> OOB q0 (up to 4095),
// stomped p1/lsum -> 1.8e10 absmax. Everything else unchanged from R6:
// attn = LDS-staged K/V + KV-split x2, lb(256,3), packed half-swap
// P-transpose; gemm_out 512-thr/8-wave; fused prep; frag-order layouts.

namespace {

typedef short bfr __attribute__((ext_vector_type(8)));   // 8 bf16 = 4 VGPR
typedef short s4v __attribute__((ext_vector_type(4)));
typedef unsigned u4v __attribute__((ext_vector_type(4)));
typedef float accf __attribute__((ext_vector_type(16)));

#define MFMA32(a, b, c) __builtin_amdgcn_mfma_f32_32x32x16_bf16(a, b, c, 0, 0, 0)

__device__ inline short f2bf(float f) {  // RNE
    unsigned u = __float_as_uint(f);
    u += 0x7fffu + ((u >> 16) & 1u);
    return (short)(u >> 16);
}
__device__ inline float bf2f(short s) {
    return __uint_as_float(((unsigned)(unsigned short)s) << 16);
}
__device__ inline float fexp2(float x) { return __builtin_amdgcn_exp2f(x); }
__device__ inline accf zero16() {
    accf z;
#pragma unroll
    for (int i = 0; i < 16; ++i) z[i] = 0.f;
    return z;
}
__device__ inline void dma16(const void* g, void* l) {
    __builtin_amdgcn_global_load_lds(
        (const __attribute__((address_space(1))) void*)g,
        (__attribute__((address_space(3))) void*)l, 16, 0, 0);
}

// ---------- prep: tobf (x,ctx) + all 4 weight transposes, one dispatch ----
__global__ __launch_bounds__(256) void prep(
    const float* __restrict__ x, const float* __restrict__ ctx,
    short* __restrict__ xb, short* __restrict__ cb,
    const float* __restrict__ Wq, const float* __restrict__ Wk,
    const float* __restrict__ Wv, const float* __restrict__ Wo,
    short* __restrict__ Wqt, short* __restrict__ Wkt,
    short* __restrict__ Wvt, short* __restrict__ Wot) {
    __shared__ short t[64][68];
    const int bx = blockIdx.x;
    if (bx < 7168) {  // elementwise fp32->bf16
        int i = bx * 256 + threadIdx.x;
        if (i < 1048576) {
            float4 v = ((const float4*)x)[i];
            s4v p = {f2bf(v.x), f2bf(v.y), f2bf(v.z), f2bf(v.w)};
            ((s4v*)xb)[i] = p;
        } else {
            int j = i - 1048576;
            float4 v = ((const float4*)ctx)[j];
            s4v p = {f2bf(v.x), f2bf(v.y), f2bf(v.z), f2bf(v.w)};
            ((s4v*)cb)[j] = p;
        }
        return;
    }
    const int idx = bx - 7168;  // 0..1023
    const int z = idx >> 8, gy = (idx >> 4) & 15, gx = idx & 15;
    const float* W;
    short* Wt;
    int K;
    switch (z) {
        case 0: W = Wq; Wt = Wqt; K = 1024; break;
        case 1: W = Wk; Wt = Wkt; K = 768; break;
        case 2: W = Wv; Wt = Wvt; K = 768; break;
        default: W = Wo; Wt = Wot; K = 1024; break;
    }
    const int k0 = gy * 64;
    if (k0 >= K) return;
    const int tid = threadIdx.x;
    const int n0 = gx * 64;
    const int kr = tid >> 4, nc = (tid & 15) * 4;
#pragma unroll
    for (int rep = 0; rep < 4; ++rep) {
        int k = kr + rep * 16;
        float4 v = *(const float4*)&W[(size_t)(k0 + k) * 1024 + n0 + nc];
        t[nc + 0][k] = f2bf(v.x);
        t[nc + 1][k] = f2bf(v.y);
        t[nc + 2][k] = f2bf(v.z);
        t[nc + 3][k] = f2bf(v.w);
    }
    __syncthreads();
    const int nr = tid >> 4, kc = (tid & 15) * 4;
#pragma unroll
    for (int rep = 0; rep < 4; ++rep) {
        int n = nr + rep * 16;
        s4v p = {t[n][kc], t[n][kc + 1], t[n][kc + 2], t[n][kc + 3]};
        *(s4v*)&Wt[(size_t)(n0 + n) * K + k0 + kc] = p;
    }
}

// ---------- fused Q/K/V projection GEMM, blockIdx.z selects ----------
__global__ __launch_bounds__(256) void gemm_qkv(
    const short* __restrict__ xb, const short* __restrict__ cb,
    const short* __restrict__ Wqt, const short* __restrict__ Wkt,
    const short* __restrict__ Wvt, const float* __restrict__ bq,
    const float* __restrict__ bk, const float* __restrict__ bv,
    short* __restrict__ Qf, short* __restrict__ Kf, short* __restrict__ Vt,
    float qscale) {
    const int z = blockIdx.z;
    const short* A  = (z == 0) ? xb : cb;
    const short* Bt = (z == 0) ? Wqt : ((z == 1) ? Wkt : Wvt);
    const float* bias = (z == 0) ? bq : ((z == 1) ? bk : bv);
    const int K = (z == 0) ? 1024 : 768;
    const float scale = (z == 0) ? qscale : 1.f;
    short* out = (z == 0) ? Qf : ((z == 1) ? Kf : Vt);

    __shared__ short As[4096];
    __shared__ short Bs[4096];
    const int t = threadIdx.x, lane = t & 63, w = t >> 6;
    const int lm = lane & 31, h2 = lane >> 5;
    const int wm = w & 1, wn = w >> 1;
    const int m0 = blockIdx.y * 128, n0 = blockIdx.x * 128;

    const int srow = t >> 2, scol = (t & 3) * 8;
    const short* ga = A + (size_t)(m0 + srow) * K + scol;
    const short* gb = Bt + (size_t)(n0 + srow) * K + scol;
    short* lA = As + w * 512;
    short* lB = Bs + w * 512;

    const int aoff = (wm * 64 + lm) * 32 + h2 * 8;
    const int boff = (wn * 64 + lm) * 32 + h2 * 8;

    accf acc[2][2] = {zero16(), zero16(), zero16(), zero16()};

    for (int kt = 0; kt < K; kt += 32) {
        __syncthreads();
        dma16(ga + kt, lA);
        dma16(ga + (size_t)64 * K + kt, lA + 2048);
        dma16(gb + kt, lB);
        dma16(gb + (size_t)64 * K + kt, lB + 2048);
        __syncthreads();
#pragma unroll
        for (int kk = 0; kk < 32; kk += 16) {
            bfr a0 = *(const bfr*)&As[aoff + kk];
            bfr a1 = *(const bfr*)&As[aoff + 1024 + kk];
            bfr b0 = *(const bfr*)&Bs[boff + kk];
            bfr b1 = *(const bfr*)&Bs[boff + 1024 + kk];
            acc[0][0] = MFMA32(a0, b0, acc[0][0]);
            acc[0][1] = MFMA32(a0, b1, acc[0][1]);
            acc[1][0] = MFMA32(a1, b0, acc[1][0]);
            acc[1][1] = MFMA32(a1, b1, acc[1][1]);
        }
    }

#pragma unroll
    for (int nt = 0; nt < 2; ++nt) {
        const int n = n0 + wn * 64 + nt * 32 + lm;
        const float bn = bias[n];
        const int hh = n >> 6, dd = n & 63;
#pragma unroll
        for (int mt = 0; mt < 2; ++mt) {
            const int mbase = m0 + wm * 64 + mt * 32 + 4 * h2;
            if (z != 2) {
                const int cb2 = (dd >> 4) * 512 + ((dd >> 3) & 1) * 256 + (dd & 7);
#pragma unroll
                for (int r = 0; r < 16; ++r) {
                    const int m = mbase + (r & 3) + 8 * (r >> 2);
                    const int bb = m >> 11, q = m & 2047;
                    float v = (acc[mt][nt][r] + bn) * scale;
                    out[((size_t)((bb * 16 + hh) * 64 + (q >> 5))) * 2048 +
                        cb2 + (q & 31) * 8] = f2bf(v);
                }
            } else {
                const int dblk = dd >> 5, lmv = dd & 31;
#pragma unroll
                for (int g = 0; g < 4; ++g) {
                    const int m = mbase + 8 * g;
                    const int bb = m >> 11, s = m & 2047;
                    const int kvt = s >> 6, kc = (s >> 4) & 3;
                    const int h2v = (s >> 3) & 1, j0 = s & 7;
                    s4v p = {f2bf(acc[mt][nt][4 * g + 0] + bn),
                             f2bf(acc[mt][nt][4 * g + 1] + bn),
                             f2bf(acc[mt][nt][4 * g + 2] + bn),
                             f2bf(acc[mt][nt][4 * g + 3] + bn)};
                    *(s4v*)(out +
                            ((size_t)(((bb * 16 + hh) * 32 + kvt) * 2 + dblk)) * 2048 +
                            kc * 512 + h2v * 256 + lmv * 8 + j0) = p;
                }
            }
        }
    }
}

// ---------- output GEMM (512 thr, 8 waves, wave tile 64x32) ----------
__global__ __launch_bounds__(512) void gemm_out(
    const short* __restrict__ A, const short* __restrict__ Bt,
    const float* __restrict__ bias, float* __restrict__ out, int K) {
    __shared__ short As[4096];
    __shared__ short Bs[4096];
    const int t = threadIdx.x, lane = t & 63, w = t >> 6;  // w 0..7
    const int lm = lane & 31, h2 = lane >> 5;
    const int wm = w & 1, wn = w >> 1;  // wm: 64-row half, wn: 32-col quarter
    const int m0 = blockIdx.y * 128, n0 = blockIdx.x * 128;

    const int srow = t >> 2, scol = (t & 3) * 8;  // 512 thr cover full tile
    const short* ga = A + (size_t)(m0 + srow) * K + scol;
    const short* gb = Bt + (size_t)(n0 + srow) * K + scol;
    short* lA = As + w * 512;
    short* lB = Bs + w * 512;

    const int aoff = (wm * 64 + lm) * 32 + h2 * 8;
    const int boff = (wn * 32 + lm) * 32 + h2 * 8;

    accf acc[2] = {zero16(), zero16()};

    for (int kt = 0; kt < K; kt += 32) {
        __syncthreads();
        dma16(ga + kt, lA);
        dma16(gb + kt, lB);
        __syncthreads();
#pragma unroll
        for (int kk = 0; kk < 32; kk += 16) {
            bfr a0 = *(const bfr*)&As[aoff + kk];
            bfr a1 = *(const bfr*)&As[aoff + 1024 + kk];
            bfr b0 = *(const bfr*)&Bs[boff + kk];
            acc[0] = MFMA32(a0, b0, acc[0]);
            acc[1] = MFMA32(a1, b0, acc[1]);
        }
    }

    const int n = n0 + wn * 32 + lm;
    const float bn = bias[n];
#pragma unroll
    for (int mt = 0; mt < 2; ++mt) {
        const int mbase = m0 + wm * 64 + mt * 32 + 4 * h2;
#pragma unroll
        for (int r = 0; r < 16; ++r) {
            const int m = mbase + (r & 3) + 8 * (r >> 2);
            out[(size_t)m * 1024 + n] = acc[mt][r] + bn;
        }
    }
}

// ---------- flash attention: LDS-staged K/V + KV-split x2 ----------
// bid = ((qb*2+split)<<5)|hidx; 1024 blocks (qb 0..15!), 4 waves,
// 32 q-rows/wave, 16 iters of 64 kv. Unnormalized partials + l sums.
__global__ __launch_bounds__(256, 3) void attn(
    const short* __restrict__ Qf, const short* __restrict__ Kf,
    const short* __restrict__ Vt, short* __restrict__ part,
    float* __restrict__ lsum) {
    __shared__ short smem[16384];  // 2 bufs x (K 4KB + V 4KB) = 32 KB
    const int bid = blockIdx.x;
    const int hidx = bid & 31, qs = bid >> 5;
    const int split = qs & 1, qb = qs >> 1;
    const int b = hidx >> 4, h = hidx & 15;
    const int lane = threadIdx.x & 63, wv = threadIdx.x >> 6;
    const int lm = lane & 31, h2 = lane >> 5;
    const bool hb = h2 != 0;
    const int q0 = qb * 128 + wv * 32;

    const short* qbase =
        Qf + ((size_t)(hidx * 64 + (q0 >> 5))) * 2048 + lane * 8;
    bfr qf[4];
#pragma unroll
    for (int kc = 0; kc < 4; ++kc) qf[kc] = *(const bfr*)(qbase + kc * 512);

    // wave w stages quarter w of each iter's 16 KB (K 8KB | V 8KB)
    const short* khead = Kf + (size_t)hidx * 131072 + split * 65536;
    const short* vhead = Vt + (size_t)hidx * 131072 + split * 65536;
    const short* gsrc =
        ((wv < 2) ? (khead + wv * 2048) : (vhead + (wv - 2) * 2048)) + lane * 8;

#pragma unroll
    for (int i = 0; i < 4; ++i)
        dma16(gsrc + i * 512, &smem[wv * 2048 + i * 512]);

    accf oa0 = zero16(), oa1 = zero16();
    float la0 = 0.f, la1 = 0.f;

#pragma unroll 1
    for (int it = 0; it < 16; ++it) {
        const int p = it & 1;
        __syncthreads();  // buf p DMA drained (vmcnt(0) before s_barrier)
        if (it + 1 < 16) {
            const short* gn = gsrc + (size_t)(it + 1) * 4096;
            short* ln = &smem[(1 - p) * 8192 + wv * 2048];
#pragma unroll
            for (int i = 0; i < 4; ++i) dma16(gn + i * 512, ln + i * 512);
        }
        const short* kb = &smem[p * 8192];
        bfr kf0[4], kf1[4], vf0[4], vf1[4];
#pragma unroll
        for (int kc = 0; kc < 4; ++kc) {
            kf0[kc] = *(const bfr*)&kb[kc * 512 + lane * 8];
            kf1[kc] = *(const bfr*)&kb[2048 + kc * 512 + lane * 8];
            vf0[kc] = *(const bfr*)&kb[4096 + kc * 512 + lane * 8];
            vf1[kc] = *(const bfr*)&kb[6144 + kc * 512 + lane * 8];
        }
        accf s0 = zero16(), s1 = zero16();
#pragma unroll
        for (int kc = 0; kc < 4; ++kc) {
            s0 = MFMA32(kf0[kc], qf[kc], s0);
            s1 = MFMA32(kf1[kc], qf[kc], s1);
        }

#pragma unroll
        for (int i = 0; i < 16; ++i) s0[i] = fexp2(s0[i]);
#pragma unroll
        for (int i = 0; i < 16; ++i) s1[i] = fexp2(s1[i]);
#pragma unroll
        for (int i = 0; i < 16; ++i) {
            if (i & 1) la1 += s0[i] + s1[i];
            else       la0 += s0[i] + s1[i];
        }

        // packed half-swap transpose: pack bf16 pairs (v_perm trunc),
        // exchange 2 words across the 32-lane halves, select packed.
        bfr pb[4];
#pragma unroll
        for (int kc = 0; kc < 4; ++kc) {
            const accf& s = (kc < 2) ? s0 : s1;
            const int base = 8 * (kc & 1);
            unsigned Lw0 = __builtin_amdgcn_perm(__float_as_uint(s[base + 1]),
                                                 __float_as_uint(s[base + 0]),
                                                 0x07060302u);
            unsigned Lw1 = __builtin_amdgcn_perm(__float_as_uint(s[base + 3]),
                                                 __float_as_uint(s[base + 2]),
                                                 0x07060302u);
            unsigned Hw0 = __builtin_amdgcn_perm(__float_as_uint(s[base + 5]),
                                                 __float_as_uint(s[base + 4]),
                                                 0x07060302u);
            unsigned Hw1 = __builtin_amdgcn_perm(__float_as_uint(s[base + 7]),
                                                 __float_as_uint(s[base + 6]),
                                                 0x07060302u);
            unsigned c0 = hb ? Lw0 : Hw0;
            unsigned c1 = hb ? Lw1 : Hw1;
            unsigned r0 = (unsigned)__shfl_xor((int)c0, 32);
            unsigned r1 = (unsigned)__shfl_xor((int)c1, 32);
            u4v pw = {hb ? r0 : Lw0, hb ? r1 : Lw1,
                      hb ? Hw0 : r0, hb ? Hw1 : r1};
            pb[kc] = __builtin_bit_cast(bfr, pw);
        }

#pragma unroll
        for (int kc = 0; kc < 4; ++kc) {
            oa0 = MFMA32(vf0[kc], pb[kc], oa0);
            oa1 = MFMA32(vf1[kc], pb[kc], oa1);
        }
    }

    float ls = la0 + la1;
    ls += __shfl_xor(ls, 32);
    if (!hb) lsum[((size_t)(split * 2 + b) * 16 + h) * 2048 + q0 + lm] = ls;

    short* orow = part + (size_t)split * 4194304 +
                  (size_t)(b * 2048 + q0 + lm) * 1024 + h * 64;
#pragma unroll
    for (int dt = 0; dt < 2; ++dt) {
        const accf& oa = dt ? oa1 : oa0;
#pragma unroll
        for (int g = 0; g < 4; ++g) {
            const int d0 = dt * 32 + 4 * h2 + 8 * g;
            s4v p = {f2bf(oa[4 * g + 0]), f2bf(oa[4 * g + 1]),
                     f2bf(oa[4 * g + 2]), f2bf(oa[4 * g + 3])};
            *(s4v*)(orow + d0) = p;
        }
    }
}

// ---------- combine splits: ao = (P0 + P1) / (l0 + l1) ----------
__global__ __launch_bounds__(256) void combine(
    const short* __restrict__ p0, const short* __restrict__ p1,
    const float* __restrict__ lsum, short* __restrict__ ao) {
    const int t = blockIdx.x * 256 + threadIdx.x;
    const int col8 = t & 127, m = t >> 7;
    const int h = col8 >> 3;
    const int b = m >> 11, q = m & 2047;
    const float l0 = lsum[((size_t)(0 + b) * 16 + h) * 2048 + q];
    const float l1 = lsum[((size_t)(2 + b) * 16 + h) * 2048 + q];
    const float inv = 1.f / (l0 + l1);
    const size_t e0 = (size_t)m * 1024 + col8 * 8;
    bfr a = *(const bfr*)(p0 + e0);
    bfr c = *(const bfr*)(p1 + e0);
    bfr r;
#pragma unroll
    for (int j = 0; j < 8; ++j) r[j] = f2bf((bf2f(a[j]) + bf2f(c[j])) * inv);
    *(bfr*)(ao + e0) = r;
}

}  // namespace

extern "C" void kernel_launch(void* const* d_in, const int* in_sizes, int n_in,
                              void* d_out, int out_size, void* d_ws,
                              size_t ws_size, hipStream_t stream) {
    const float* x   = (const float*)d_in[0];
    const float* ctx = (const float*)d_in[1];
    const float* Wq  = (const float*)d_in[2];
    const float* bq  = (const float*)d_in[3];
    const float* Wk  = (const float*)d_in[4];
    const float* bk  = (const float*)d_in[5];
    const float* Wv  = (const float*)d_in[6];
    const float* bv  = (const float*)d_in[7];
    const float* Wo  = (const float*)d_in[8];
    const float* bo  = (const float*)d_in[9];

    short* xb  = (short*)d_ws;               // [4096,1024]; reused as ao later
    short* cb  = xb + (size_t)4096 * 1024;
    short* Wqt = cb + (size_t)4096 * 768;
    short* Wkt = Wqt + (size_t)1024 * 1024;
    short* Wvt = Wkt + (size_t)1024 * 768;
    short* Wot = Wvt + (size_t)1024 * 768;
    short* Qf  = Wot + (size_t)1024 * 1024;  // frag-order, pre-scaled
    short* Kf  = Qf + (size_t)4096 * 1024;   // frag-order
    short* Vt  = Kf + (size_t)4096 * 1024;   // frag-order V^T
    short* p0  = Vt + (size_t)4096 * 1024;   // split partials (unnormalized)
    short* p1  = p0 + (size_t)4096 * 1024;
    float* lsum = (float*)(p1 + (size_t)4096 * 1024);  // [2][2][16][2048]

    prep<<<8192, 256, 0, stream>>>(x, ctx, xb, cb, Wq, Wk, Wv, Wo,
                                   Wqt, Wkt, Wvt, Wot);

    const float qscale = 0.125f * 1.44269504088896f;
    gemm_qkv<<<dim3(8, 32, 3), 256, 0, stream>>>(xb, cb, Wqt, Wkt, Wvt,
                                                 bq, bk, bv, Qf, Kf, Vt,
                                                 qscale);

    attn<<<1024, 256, 0, stream>>>(Qf, Kf, Vt, p0, lsum);  // 16qb x 2split x 32hidx
    combine<<<2048, 256, 0, stream>>>(p0, p1, lsum, xb);   // xb becomes ao

    gemm_out<<<dim3(8, 32), 512, 0, stream>>>(xb, Wot, bo, (float*)d_out, 1024);
}

// Round 8
// 216.935 us; speedup vs baseline: 5.1364x; 1.0273x over previous
//
#include <hip/hip_runtime.h>
#include <math.h>

// CrossAttention B=2,S=2048,E=1024,H=16,Dh=64,NC=768 — fp32 in/out.
// R8: GEMM K-loops double-buffered attn-style (one barrier/iter, DMA(k+1)
// issued before computing k — R7's serial barrier-dma-barrier-compute loop
// exposed full DMA latency: MfmaUtil 14%, VALUBusy 8%, all idle) + LDS
// XOR-swizzle on staging (R7 SQ_LDS_BANK_CONFLICT 7.9e6 ≈ 2x read cost:
// 64B/lane row stride hit 4 of 8 bank-quads). Staging source chunk
// sigma(t)=t^((t>>3)&7) -> slot t; reads at slot c^((lm>>1)&7). attn/prep/
// combine unchanged from R7.

namespace {

typedef short bfr __attribute__((ext_vector_type(8)));   // 8 bf16 = 4 VGPR
typedef short s4v __attribute__((ext_vector_type(4)));
typedef unsigned u4v __attribute__((ext_vector_type(4)));
typedef float accf __attribute__((ext_vector_type(16)));

#define MFMA32(a, b, c) __builtin_amdgcn_mfma_f32_32x32x16_bf16(a, b, c, 0, 0, 0)

__device__ inline short f2bf(float f) {  // RNE
    unsigned u = __float_as_uint(f);
    u += 0x7fffu + ((u >> 16) & 1u);
    return (short)(u >> 16);
}
__device__ inline float bf2f(short s) {
    return __uint_as_float(((unsigned)(unsigned short)s) << 16);
}
__device__ inline float fexp2(float x) { return __builtin_amdgcn_exp2f(x); }
__device__ inline accf zero16() {
    accf z;
#pragma unroll
    for (int i = 0; i < 16; ++i) z[i] = 0.f;
    return z;
}
__device__ inline void dma16(const void* g, void* l) {
    __builtin_amdgcn_global_load_lds(
        (const __attribute__((address_space(1))) void*)g,
        (__attribute__((address_space(3))) void*)l, 16, 0, 0);
}

// ---------- prep: tobf (x,ctx) + all 4 weight transposes, one dispatch ----
__global__ __launch_bounds__(256) void prep(
    const float* __restrict__ x, const float* __restrict__ ctx,
    short* __restrict__ xb, short* __restrict__ cb,
    const float* __restrict__ Wq, const float* __restrict__ Wk,
    const float* __restrict__ Wv, const float* __restrict__ Wo,
    short* __restrict__ Wqt, short* __restrict__ Wkt,
    short* __restrict__ Wvt, short* __restrict__ Wot) {
    __shared__ short t[64][68];
    const int bx = blockIdx.x;
    if (bx < 7168) {  // elementwise fp32->bf16
        int i = bx * 256 + threadIdx.x;
        if (i < 1048576) {
            float4 v = ((const float4*)x)[i];
            s4v p = {f2bf(v.x), f2bf(v.y), f2bf(v.z), f2bf(v.w)};
            ((s4v*)xb)[i] = p;
        } else {
            int j = i - 1048576;
            float4 v = ((const float4*)ctx)[j];
            s4v p = {f2bf(v.x), f2bf(v.y), f2bf(v.z), f2bf(v.w)};
            ((s4v*)cb)[j] = p;
        }
        return;
    }
    const int idx = bx - 7168;  // 0..1023
    const int z = idx >> 8, gy = (idx >> 4) & 15, gx = idx & 15;
    const float* W;
    short* Wt;
    int K;
    switch (z) {
        case 0: W = Wq; Wt = Wqt; K = 1024; break;
        case 1: W = Wk; Wt = Wkt; K = 768; break;
        case 2: W = Wv; Wt = Wvt; K = 768; break;
        default: W = Wo; Wt = Wot; K = 1024; break;
    }
    const int k0 = gy * 64;
    if (k0 >= K) return;
    const int tid = threadIdx.x;
    const int n0 = gx * 64;
    const int kr = tid >> 4, nc = (tid & 15) * 4;
#pragma unroll
    for (int rep = 0; rep < 4; ++rep) {
        int k = kr + rep * 16;
        float4 v = *(const float4*)&W[(size_t)(k0 + k) * 1024 + n0 + nc];
        t[nc + 0][k] = f2bf(v.x);
        t[nc + 1][k] = f2bf(v.y);
        t[nc + 2][k] = f2bf(v.z);
        t[nc + 3][k] = f2bf(v.w);
    }
    __syncthreads();
    const int nr = tid >> 4, kc = (tid & 15) * 4;
#pragma unroll
    for (int rep = 0; rep < 4; ++rep) {
        int n = nr + rep * 16;
        s4v p = {t[n][kc], t[n][kc + 1], t[n][kc + 2], t[n][kc + 3]};
        *(s4v*)&Wt[(size_t)(n0 + n) * K + k0 + kc] = p;
    }
}

// ---------- fused Q/K/V projection GEMM, dbuf K-loop + swizzled LDS -------
__global__ __launch_bounds__(256) void gemm_qkv(
    const short* __restrict__ xb, const short* __restrict__ cb,
    const short* __restrict__ Wqt, const short* __restrict__ Wkt,
    const short* __restrict__ Wvt, const float* __restrict__ bq,
    const float* __restrict__ bk, const float* __restrict__ bv,
    short* __restrict__ Qf, short* __restrict__ Kf, short* __restrict__ Vt,
    float qscale) {
    const int z = blockIdx.z;
    const short* A  = (z == 0) ? xb : cb;
    const short* Bt = (z == 0) ? Wqt : ((z == 1) ? Wkt : Wvt);
    const float* bias = (z == 0) ? bq : ((z == 1) ? bk : bv);
    const int K = (z == 0) ? 1024 : 768;
    const int NIT = K / 32;
    const float scale = (z == 0) ? qscale : 1.f;
    short* out = (z == 0) ? Qf : ((z == 1) ? Kf : Vt);

    __shared__ short As[8192];  // 2 x 4096 (double buffer)
    __shared__ short Bs[8192];
    const int t = threadIdx.x, lane = t & 63, w = t >> 6;
    const int lm = lane & 31, h2 = lane >> 5;
    const int wm = w & 1, wn = w >> 1;
    const int m0 = blockIdx.y * 128, n0 = blockIdx.x * 128;

    // staging: slot t holds global chunk sigma(t) = t ^ ((t>>3)&7)
    const int st = t ^ ((t >> 3) & 7);
    const int srow = st >> 2, scol = (st & 3) * 8;
    const short* ga = A + (size_t)(m0 + srow) * K + scol;
    const short* gb = Bt + (size_t)(n0 + srow) * K + scol;

    // read: slot = chunk ^ xorv, chunk = row*4 + colchunk
    const int xorv = (lm >> 1) & 7;
    const int rA0 = wm * 64 + lm, rB0 = wn * 64 + lm;

    accf acc[2][2] = {zero16(), zero16(), zero16(), zero16()};

    // prologue: stage iter 0 into buf 0
    dma16(ga, &As[w * 512]);
    dma16(ga + (size_t)64 * K, &As[2048 + w * 512]);
    dma16(gb, &Bs[w * 512]);
    dma16(gb + (size_t)64 * K, &Bs[2048 + w * 512]);

#pragma unroll 1
    for (int it = 0; it < NIT; ++it) {
        const int p = it & 1;
        __syncthreads();  // drains DMA for buf p (vmcnt0 before s_barrier)
        if (it + 1 < NIT) {
            const int kt = (it + 1) * 32;
            short* lA = &As[(1 - p) * 4096 + w * 512];
            short* lB = &Bs[(1 - p) * 4096 + w * 512];
            dma16(ga + kt, lA);
            dma16(ga + (size_t)64 * K + kt, lA + 2048);
            dma16(gb + kt, lB);
            dma16(gb + (size_t)64 * K + kt, lB + 2048);
        }
        const short* bA = &As[p * 4096];
        const short* bB = &Bs[p * 4096];
#pragma unroll
        for (int kk8 = 0; kk8 < 4; kk8 += 2) {
            bfr a0 = *(const bfr*)&bA[((rA0 * 4 + h2 + kk8) ^ xorv) * 8];
            bfr a1 = *(const bfr*)&bA[(((rA0 + 32) * 4 + h2 + kk8) ^ xorv) * 8];
            bfr b0 = *(const bfr*)&bB[((rB0 * 4 + h2 + kk8) ^ xorv) * 8];
            bfr b1 = *(const bfr*)&bB[(((rB0 + 32) * 4 + h2 + kk8) ^ xorv) * 8];
            acc[0][0] = MFMA32(a0, b0, acc[0][0]);
            acc[0][1] = MFMA32(a0, b1, acc[0][1]);
            acc[1][0] = MFMA32(a1, b0, acc[1][0]);
            acc[1][1] = MFMA32(a1, b1, acc[1][1]);
        }
    }

#pragma unroll
    for (int nt = 0; nt < 2; ++nt) {
        const int n = n0 + wn * 64 + nt * 32 + lm;
        const float bn = bias[n];
        const int hh = n >> 6, dd = n & 63;
#pragma unroll
        for (int mt = 0; mt < 2; ++mt) {
            const int mbase = m0 + wm * 64 + mt * 32 + 4 * h2;
            if (z != 2) {
                const int cb2 = (dd >> 4) * 512 + ((dd >> 3) & 1) * 256 + (dd & 7);
#pragma unroll
                for (int r = 0; r < 16; ++r) {
                    const int m = mbase + (r & 3) + 8 * (r >> 2);
                    const int bb = m >> 11, q = m & 2047;
                    float v = (acc[mt][nt][r] + bn) * scale;
                    out[((size_t)((bb * 16 + hh) * 64 + (q >> 5))) * 2048 +
                        cb2 + (q & 31) * 8] = f2bf(v);
                }
            } else {
                const int dblk = dd >> 5, lmv = dd & 31;
#pragma unroll
                for (int g = 0; g < 4; ++g) {
                    const int m = mbase + 8 * g;
                    const int bb = m >> 11, s = m & 2047;
                    const int kvt = s >> 6, kc = (s >> 4) & 3;
                    const int h2v = (s >> 3) & 1, j0 = s & 7;
                    s4v p = {f2bf(acc[mt][nt][4 * g + 0] + bn),
                             f2bf(acc[mt][nt][4 * g + 1] + bn),
                             f2bf(acc[mt][nt][4 * g + 2] + bn),
                             f2bf(acc[mt][nt][4 * g + 3] + bn)};
                    *(s4v*)(out +
                            ((size_t)(((bb * 16 + hh) * 32 + kvt) * 2 + dblk)) * 2048 +
                            kc * 512 + h2v * 256 + lmv * 8 + j0) = p;
                }
            }
        }
    }
}

// ---------- output GEMM (512 thr, 8 waves), dbuf + swizzled LDS ----------
__global__ __launch_bounds__(512) void gemm_out(
    const short* __restrict__ A, const short* __restrict__ Bt,
    const float* __restrict__ bias, float* __restrict__ out, int K) {
    __shared__ short As[8192];  // 2 x 4096
    __shared__ short Bs[8192];
    const int t = threadIdx.x, lane = t & 63, w = t >> 6;  // w 0..7
    const int lm = lane & 31, h2 = lane >> 5;
    const int wm = w & 1, wn = w >> 1;  // wm: 64-row half, wn: 32-col quarter
    const int m0 = blockIdx.y * 128, n0 = blockIdx.x * 128;
    const int NIT = K / 32;

    const int st = t ^ ((t >> 3) & 7);
    const int srow = st >> 2, scol = (st & 3) * 8;  // 512 thr cover full tile
    const short* ga = A + (size_t)(m0 + srow) * K + scol;
    const short* gb = Bt + (size_t)(n0 + srow) * K + scol;

    const int xorv = (lm >> 1) & 7;
    const int rA0 = wm * 64 + lm, rB0 = wn * 32 + lm;

    accf acc[2] = {zero16(), zero16()};

    dma16(ga, &As[w * 512]);
    dma16(gb, &Bs[w * 512]);

#pragma unroll 1
    for (int it = 0; it < NIT; ++it) {
        const int p = it & 1;
        __syncthreads();
        if (it + 1 < NIT) {
            const int kt = (it + 1) * 32;
            dma16(ga + kt, &As[(1 - p) * 4096 + w * 512]);
            dma16(gb + kt, &Bs[(1 - p) * 4096 + w * 512]);
        }
        const short* bA = &As[p * 4096];
        const short* bB = &Bs[p * 4096];
#pragma unroll
        for (int kk8 = 0; kk8 < 4; kk8 += 2) {
            bfr a0 = *(const bfr*)&bA[((rA0 * 4 + h2 + kk8) ^ xorv) * 8];
            bfr a1 = *(const bfr*)&bA[(((rA0 + 32) * 4 + h2 + kk8) ^ xorv) * 8];
            bfr b0 = *(const bfr*)&bB[((rB0 * 4 + h2 + kk8) ^ xorv) * 8];
            acc[0] = MFMA32(a0, b0, acc[0]);
            acc[1] = MFMA32(a1, b0, acc[1]);
        }
    }

    const int n = n0 + wn * 32 + lm;
    const float bn = bias[n];
#pragma unroll
    for (int mt = 0; mt < 2; ++mt) {
        const int mbase = m0 + wm * 64 + mt * 32 + 4 * h2;
#pragma unroll
        for (int r = 0; r < 16; ++r) {
            const int m = mbase + (r & 3) + 8 * (r >> 2);
            out[(size_t)m * 1024 + n] = acc[mt][r] + bn;
        }
    }
}

// ---------- flash attention: LDS-staged K/V + KV-split x2 (unchanged) -----
__global__ __launch_bounds__(256, 3) void attn(
    const short* __restrict__ Qf, const short* __restrict__ Kf,
    const short* __restrict__ Vt, short* __restrict__ part,
    float* __restrict__ lsum) {
    __shared__ short smem[16384];  // 2 bufs x (K 4KB + V 4KB) = 32 KB
    const int bid = blockIdx.x;
    const int hidx = bid & 31, qs = bid >> 5;
    const int split = qs & 1, qb = qs >> 1;
    const int b = hidx >> 4, h = hidx & 15;
    const int lane = threadIdx.x & 63, wv = threadIdx.x >> 6;
    const int lm = lane & 31, h2 = lane >> 5;
    const bool hb = h2 != 0;
    const int q0 = qb * 128 + wv * 32;

    const short* qbase =
        Qf + ((size_t)(hidx * 64 + (q0 >> 5))) * 2048 + lane * 8;
    bfr qf[4];
#pragma unroll
    for (int kc = 0; kc < 4; ++kc) qf[kc] = *(const bfr*)(qbase + kc * 512);

    const short* khead = Kf + (size_t)hidx * 131072 + split * 65536;
    const short* vhead = Vt + (size_t)hidx * 131072 + split * 65536;
    const short* gsrc =
        ((wv < 2) ? (khead + wv * 2048) : (vhead + (wv - 2) * 2048)) + lane * 8;

#pragma unroll
    for (int i = 0; i < 4; ++i)
        dma16(gsrc + i * 512, &smem[wv * 2048 + i * 512]);

    accf oa0 = zero16(), oa1 = zero16();
    float la0 = 0.f, la1 = 0.f;

#pragma unroll 1
    for (int it = 0; it < 16; ++it) {
        const int p = it & 1;
        __syncthreads();  // buf p DMA drained (vmcnt(0) before s_barrier)
        if (it + 1 < 16) {
            const short* gn = gsrc + (size_t)(it + 1) * 4096;
            short* ln = &smem[(1 - p) * 8192 + wv * 2048];
#pragma unroll
            for (int i = 0; i < 4; ++i) dma16(gn + i * 512, ln + i * 512);
        }
        const short* kb = &smem[p * 8192];
        bfr kf0[4], kf1[4], vf0[4], vf1[4];
#pragma unroll
        for (int kc = 0; kc < 4; ++kc) {
            kf0[kc] = *(const bfr*)&kb[kc * 512 + lane * 8];
            kf1[kc] = *(const bfr*)&kb[2048 + kc * 512 + lane * 8];
            vf0[kc] = *(const bfr*)&kb[4096 + kc * 512 + lane * 8];
            vf1[kc] = *(const bfr*)&kb[6144 + kc * 512 + lane * 8];
        }
        accf s0 = zero16(), s1 = zero16();
#pragma unroll
        for (int kc = 0; kc < 4; ++kc) {
            s0 = MFMA32(kf0[kc], qf[kc], s0);
            s1 = MFMA32(kf1[kc], qf[kc], s1);
        }

#pragma unroll
        for (int i = 0; i < 16; ++i) s0[i] = fexp2(s0[i]);
#pragma unroll
        for (int i = 0; i < 16; ++i) s1[i] = fexp2(s1[i]);
#pragma unroll
        for (int i = 0; i < 16; ++i) {
            if (i & 1) la1 += s0[i] + s1[i];
            else       la0 += s0[i] + s1[i];
        }

        // packed half-swap transpose
        bfr pb[4];
#pragma unroll
        for (int kc = 0; kc < 4; ++kc) {
            const accf& s = (kc < 2) ? s0 : s1;
            const int base = 8 * (kc & 1);
            unsigned Lw0 = __builtin_amdgcn_perm(__float_as_uint(s[base + 1]),
                                                 __float_as_uint(s[base + 0]),
                                                 0x07060302u);
            unsigned Lw1 = __builtin_amdgcn_perm(__float_as_uint(s[base + 3]),
                                                 __float_as_uint(s[base + 2]),
                                                 0x07060302u);
            unsigned Hw0 = __builtin_amdgcn_perm(__float_as_uint(s[base + 5]),
                                                 __float_as_uint(s[base + 4]),
                                                 0x07060302u);
            unsigned Hw1 = __builtin_amdgcn_perm(__float_as_uint(s[base + 7]),
                                                 __float_as_uint(s[base + 6]),
                                                 0x07060302u);
            unsigned c0 = hb ? Lw0 : Hw0;
            unsigned c1 = hb ? Lw1 : Hw1;
            unsigned r0 = (unsigned)__shfl_xor((int)c0, 32);
            unsigned r1 = (unsigned)__shfl_xor((int)c1, 32);
            u4v pw = {hb ? r0 : Lw0, hb ? r1 : Lw1,
                      hb ? Hw0 : r0, hb ? Hw1 : r1};
            pb[kc] = __builtin_bit_cast(bfr, pw);
        }

#pragma unroll
        for (int kc = 0; kc < 4; ++kc) {
            oa0 = MFMA32(vf0[kc], pb[kc], oa0);
            oa1 = MFMA32(vf1[kc], pb[kc], oa1);
        }
    }

    float ls = la0 + la1;
    ls += __shfl_xor(ls, 32);
    if (!hb) lsum[((size_t)(split * 2 + b) * 16 + h) * 2048 + q0 + lm] = ls;

    short* orow = part + (size_t)split * 4194304 +
                  (size_t)(b * 2048 + q0 + lm) * 1024 + h * 64;
#pragma unroll
    for (int dt = 0; dt < 2; ++dt) {
        const accf& oa = dt ? oa1 : oa0;
#pragma unroll
        for (int g = 0; g < 4; ++g) {
            const int d0 = dt * 32 + 4 * h2 + 8 * g;
            s4v p = {f2bf(oa[4 * g + 0]), f2bf(oa[4 * g + 1]),
                     f2bf(oa[4 * g + 2]), f2bf(oa[4 * g + 3])};
            *(s4v*)(orow + d0) = p;
        }
    }
}

// ---------- combine splits: ao = (P0 + P1) / (l0 + l1) ----------
__global__ __launch_bounds__(256) void combine(
    const short* __restrict__ p0, const short* __restrict__ p1,
    const float* __restrict__ lsum, short* __restrict__ ao) {
    const int t = blockIdx.x * 256 + threadIdx.x;
    const int col8 = t & 127, m = t >> 7;
    const int h = col8 >> 3;
    const int b = m >> 11, q = m & 2047;
    const float l0 = lsum[((size_t)(0 + b) * 16 + h) * 2048 + q];
    const float l1 = lsum[((size_t)(2 + b) * 16 + h) * 2048 + q];
    const float inv = 1.f / (l0 + l1);
    const size_t e0 = (size_t)m * 1024 + col8 * 8;
    bfr a = *(const bfr*)(p0 + e0);
    bfr c = *(const bfr*)(p1 + e0);
    bfr r;
#pragma unroll
    for (int j = 0; j < 8; ++j) r[j] = f2bf((bf2f(a[j]) + bf2f(c[j])) * inv);
    *(bfr*)(ao + e0) = r;
}

}  // namespace

extern "C" void kernel_launch(void* const* d_in, const int* in_sizes, int n_in,
                              void* d_out, int out_size, void* d_ws,
                              size_t ws_size, hipStream_t stream) {
    const float* x   = (const float*)d_in[0];
    const float* ctx = (const float*)d_in[1];
    const float* Wq  = (const float*)d_in[2];
    const float* bq  = (const float*)d_in[3];
    const float* Wk  = (const float*)d_in[4];
    const float* bk  = (const float*)d_in[5];
    const float* Wv  = (const float*)d_in[6];
    const float* bv  = (const float*)d_in[7];
    const float* Wo  = (const float*)d_in[8];
    const float* bo  = (const float*)d_in[9];

    short* xb  = (short*)d_ws;               // [4096,1024]; reused as ao later
    short* cb  = xb + (size_t)4096 * 1024;
    short* Wqt = cb + (size_t)4096 * 768;
    short* Wkt = Wqt + (size_t)1024 * 1024;
    short* Wvt = Wkt + (size_t)1024 * 768;
    short* Wot = Wvt + (size_t)1024 * 768;
    short* Qf  = Wot + (size_t)1024 * 1024;  // frag-order, pre-scaled
    short* Kf  = Qf + (size_t)4096 * 1024;   // frag-order
    short* Vt  = Kf + (size_t)4096 * 1024;   // frag-order V^T
    short* p0  = Vt + (size_t)4096 * 1024;   // split partials (unnormalized)
    short* p1  = p0 + (size_t)4096 * 1024;
    float* lsum = (float*)(p1 + (size_t)4096 * 1024);  // [2][2][16][2048]

    prep<<<8192, 256, 0, stream>>>(x, ctx, xb, cb, Wq, Wk, Wv, Wo,
                                   Wqt, Wkt, Wvt, Wot);

    const float qscale = 0.125f * 1.44269504088896f;
    gemm_qkv<<<dim3(8, 32, 3), 256, 0, stream>>>(xb, cb, Wqt, Wkt, Wvt,
                                                 bq, bk, bv, Qf, Kf, Vt,
                                                 qscale);

    attn<<<1024, 256, 0, stream>>>(Qf, Kf, Vt, p0, lsum);  // 16qb x 2split x 32hidx
    combine<<<2048, 256, 0, stream>>>(p0, p1, lsum, xb);   // xb becomes ao

    gemm_out<<<dim3(8, 32), 512, 0, stream>>>(xb, Wot, bo, (float*)d_out, 1024);
}

// Round 9
// 216.688 us; speedup vs baseline: 5.1422x; 1.0011x over previous
//
#include <hip/hip_runtime.h>
#include <math.h>

// CrossAttention B=2,S=2048,E=1024,H=16,Dh=64,NC=768 — fp32 in/out.
// R9: (1) XCD-colocating swizzle for GEMM grids (bid%8 = m-tile%8 so the 8
// n-blocks sharing an A-tile land on one XCD's L2 — R8 gemm_qkv was L2-miss
// BW bound: FETCH 84.5 MB vs 19 unique, 2.33 TB/s = dispatch duration).
// Per-XCD set: 4 A-tiles (1MB) + B (2MB) < 4MB L2. (2) combine fused into
// gemm_out A-staging (p0+p1 scaled by precomputed inv[h], ds_write to same
// swizzled slots; B stays DMA) — one less dispatch, −24 MB traffic.
// attn/prep unchanged from R8.

namespace {

typedef short bfr __attribute__((ext_vector_type(8)));   // 8 bf16 = 4 VGPR
typedef short s4v __attribute__((ext_vector_type(4)));
typedef unsigned u4v __attribute__((ext_vector_type(4)));
typedef float accf __attribute__((ext_vector_type(16)));

#define MFMA32(a, b, c) __builtin_amdgcn_mfma_f32_32x32x16_bf16(a, b, c, 0, 0, 0)

__device__ inline short f2bf(float f) {  // RNE
    unsigned u = __float_as_uint(f);
    u += 0x7fffu + ((u >> 16) & 1u);
    return (short)(u >> 16);
}
__device__ inline float bf2f(short s) {
    return __uint_as_float(((unsigned)(unsigned short)s) << 16);
}
__device__ inline float fexp2(float x) { return __builtin_amdgcn_exp2f(x); }
__device__ inline accf zero16() {
    accf z;
#pragma unroll
    for (int i = 0; i < 16; ++i) z[i] = 0.f;
    return z;
}
__device__ inline void dma16(const void* g, void* l) {
    __builtin_amdgcn_global_load_lds(
        (const __attribute__((address_space(1))) void*)g,
        (__attribute__((address_space(3))) void*)l, 16, 0, 0);
}

// ---------- prep: tobf (x,ctx) + all 4 weight transposes, one dispatch ----
__global__ __launch_bounds__(256) void prep(
    const float* __restrict__ x, const float* __restrict__ ctx,
    short* __restrict__ xb, short* __restrict__ cb,
    const float* __restrict__ Wq, const float* __restrict__ Wk,
    const float* __restrict__ Wv, const float* __restrict__ Wo,
    short* __restrict__ Wqt, short* __restrict__ Wkt,
    short* __restrict__ Wvt, short* __restrict__ Wot) {
    __shared__ short t[64][68];
    const int bx = blockIdx.x;
    if (bx < 7168) {  // elementwise fp32->bf16
        int i = bx * 256 + threadIdx.x;
        if (i < 1048576) {
            float4 v = ((const float4*)x)[i];
            s4v p = {f2bf(v.x), f2bf(v.y), f2bf(v.z), f2bf(v.w)};
            ((s4v*)xb)[i] = p;
        } else {
            int j = i - 1048576;
            float4 v = ((const float4*)ctx)[j];
            s4v p = {f2bf(v.x), f2bf(v.y), f2bf(v.z), f2bf(v.w)};
            ((s4v*)cb)[j] = p;
        }
        return;
    }
    const int idx = bx - 7168;  // 0..1023
    const int z = idx >> 8, gy = (idx >> 4) & 15, gx = idx & 15;
    const float* W;
    short* Wt;
    int K;
    switch (z) {
        case 0: W = Wq; Wt = Wqt; K = 1024; break;
        case 1: W = Wk; Wt = Wkt; K = 768; break;
        case 2: W = Wv; Wt = Wvt; K = 768; break;
        default: W = Wo; Wt = Wot; K = 1024; break;
    }
    const int k0 = gy * 64;
    if (k0 >= K) return;
    const int tid = threadIdx.x;
    const int n0 = gx * 64;
    const int kr = tid >> 4, nc = (tid & 15) * 4;
#pragma unroll
    for (int rep = 0; rep < 4; ++rep) {
        int k = kr + rep * 16;
        float4 v = *(const float4*)&W[(size_t)(k0 + k) * 1024 + n0 + nc];
        t[nc + 0][k] = f2bf(v.x);
        t[nc + 1][k] = f2bf(v.y);
        t[nc + 2][k] = f2bf(v.z);
        t[nc + 3][k] = f2bf(v.w);
    }
    __syncthreads();
    const int nr = tid >> 4, kc = (tid & 15) * 4;
#pragma unroll
    for (int rep = 0; rep < 4; ++rep) {
        int n = nr + rep * 16;
        s4v p = {t[n][kc], t[n][kc + 1], t[n][kc + 2], t[n][kc + 3]};
        *(s4v*)&Wt[(size_t)(n0 + n) * K + k0 + kc] = p;
    }
}

// ---------- fused Q/K/V projection GEMM, XCD-swizzled 1D grid (768) -------
// bid: z = bid>>8; local = bid&255; m = local&31, n = local>>5
// -> bid%8 == m%8: the 8 n-blocks sharing an A-tile colocate on one XCD.
__global__ __launch_bounds__(256) void gemm_qkv(
    const short* __restrict__ xb, const short* __restrict__ cb,
    const short* __restrict__ Wqt, const short* __restrict__ Wkt,
    const short* __restrict__ Wvt, const float* __restrict__ bq,
    const float* __restrict__ bk, const float* __restrict__ bv,
    short* __restrict__ Qf, short* __restrict__ Kf, short* __restrict__ Vt,
    float qscale) {
    const int bid = blockIdx.x;
    const int z = bid >> 8;
    const int local = bid & 255;
    const short* A  = (z == 0) ? xb : cb;
    const short* Bt = (z == 0) ? Wqt : ((z == 1) ? Wkt : Wvt);
    const float* bias = (z == 0) ? bq : ((z == 1) ? bk : bv);
    const int K = (z == 0) ? 1024 : 768;
    const int NIT = K / 32;
    const float scale = (z == 0) ? qscale : 1.f;
    short* out = (z == 0) ? Qf : ((z == 1) ? Kf : Vt);

    __shared__ short As[8192];  // 2 x 4096 (double buffer)
    __shared__ short Bs[8192];
    const int t = threadIdx.x, lane = t & 63, w = t >> 6;
    const int lm = lane & 31, h2 = lane >> 5;
    const int wm = w & 1, wn = w >> 1;
    const int m0 = (local & 31) * 128, n0 = (local >> 5) * 128;

    // staging: slot t holds global chunk sigma(t) = t ^ ((t>>3)&7)
    const int st = t ^ ((t >> 3) & 7);
    const int srow = st >> 2, scol = (st & 3) * 8;
    const short* ga = A + (size_t)(m0 + srow) * K + scol;
    const short* gb = Bt + (size_t)(n0 + srow) * K + scol;

    // read: slot = chunk ^ xorv, chunk = row*4 + colchunk
    const int xorv = (lm >> 1) & 7;
    const int rA0 = wm * 64 + lm, rB0 = wn * 64 + lm;

    accf acc[2][2] = {zero16(), zero16(), zero16(), zero16()};

    // prologue: stage iter 0 into buf 0
    dma16(ga, &As[w * 512]);
    dma16(ga + (size_t)64 * K, &As[2048 + w * 512]);
    dma16(gb, &Bs[w * 512]);
    dma16(gb + (size_t)64 * K, &Bs[2048 + w * 512]);

#pragma unroll 1
    for (int it = 0; it < NIT; ++it) {
        const int p = it & 1;
        __syncthreads();  // drains DMA for buf p (vmcnt0 before s_barrier)
        if (it + 1 < NIT) {
            const int kt = (it + 1) * 32;
            short* lA = &As[(1 - p) * 4096 + w * 512];
            short* lB = &Bs[(1 - p) * 4096 + w * 512];
            dma16(ga + kt, lA);
            dma16(ga + (size_t)64 * K + kt, lA + 2048);
            dma16(gb + kt, lB);
            dma16(gb + (size_t)64 * K + kt, lB + 2048);
        }
        const short* bA = &As[p * 4096];
        const short* bB = &Bs[p * 4096];
#pragma unroll
        for (int kk8 = 0; kk8 < 4; kk8 += 2) {
            bfr a0 = *(const bfr*)&bA[((rA0 * 4 + h2 + kk8) ^ xorv) * 8];
            bfr a1 = *(const bfr*)&bA[(((rA0 + 32) * 4 + h2 + kk8) ^ xorv) * 8];
            bfr b0 = *(const bfr*)&bB[((rB0 * 4 + h2 + kk8) ^ xorv) * 8];
            bfr b1 = *(const bfr*)&bB[(((rB0 + 32) * 4 + h2 + kk8) ^ xorv) * 8];
            acc[0][0] = MFMA32(a0, b0, acc[0][0]);
            acc[0][1] = MFMA32(a0, b1, acc[0][1]);
            acc[1][0] = MFMA32(a1, b0, acc[1][0]);
            acc[1][1] = MFMA32(a1, b1, acc[1][1]);
        }
    }

#pragma unroll
    for (int nt = 0; nt < 2; ++nt) {
        const int n = n0 + wn * 64 + nt * 32 + lm;
        const float bn = bias[n];
        const int hh = n >> 6, dd = n & 63;
#pragma unroll
        for (int mt = 0; mt < 2; ++mt) {
            const int mbase = m0 + wm * 64 + mt * 32 + 4 * h2;
            if (z != 2) {
                const int cb2 = (dd >> 4) * 512 + ((dd >> 3) & 1) * 256 + (dd & 7);
#pragma unroll
                for (int r = 0; r < 16; ++r) {
                    const int m = mbase + (r & 3) + 8 * (r >> 2);
                    const int bb = m >> 11, q = m & 2047;
                    float v = (acc[mt][nt][r] + bn) * scale;
                    out[((size_t)((bb * 16 + hh) * 64 + (q >> 5))) * 2048 +
                        cb2 + (q & 31) * 8] = f2bf(v);
                }
            } else {
                const int dblk = dd >> 5, lmv = dd & 31;
#pragma unroll
                for (int g = 0; g < 4; ++g) {
                    const int m = mbase + 8 * g;
                    const int bb = m >> 11, s = m & 2047;
                    const int kvt = s >> 6, kc = (s >> 4) & 3;
                    const int h2v = (s >> 3) & 1, j0 = s & 7;
                    s4v p = {f2bf(acc[mt][nt][4 * g + 0] + bn),
                             f2bf(acc[mt][nt][4 * g + 1] + bn),
                             f2bf(acc[mt][nt][4 * g + 2] + bn),
                             f2bf(acc[mt][nt][4 * g + 3] + bn)};
                    *(s4v*)(out +
                            ((size_t)(((bb * 16 + hh) * 32 + kvt) * 2 + dblk)) * 2048 +
                            kc * 512 + h2v * 256 + lmv * 8 + j0) = p;
                }
            }
        }
    }
}

// ---------- output GEMM with fused combine (512 thr, 8 waves) ----------
// A-tile = (p0+p1)*inv staged via explicit loads + ds_write (same swizzled
// slots); B via DMA. 1D grid 256, XCD swizzle m = bid&31.
__global__ __launch_bounds__(512) void gemm_out(
    const short* __restrict__ p0, const short* __restrict__ p1,
    const float* __restrict__ lsum, const short* __restrict__ Bt,
    const float* __restrict__ bias, float* __restrict__ out) {
    constexpr int K = 1024, NIT = 32;
    __shared__ short As[8192];  // 2 x 4096
    __shared__ short Bs[8192];
    const int t = threadIdx.x, lane = t & 63, w = t >> 6;  // w 0..7
    const int lm = lane & 31, h2 = lane >> 5;
    const int wm = w & 1, wn = w >> 1;
    const int bid = blockIdx.x;
    const int m0 = (bid & 31) * 128, n0 = (bid >> 5) * 128;

    const int st = t ^ ((t >> 3) & 7);
    const int srow = st >> 2, scol = (st & 3) * 8;  // 512 thr cover full tile
    const int gm = m0 + srow;
    const int b = gm >> 11, q = gm & 2047;
    const short* pa0 = p0 + (size_t)gm * 1024 + scol;
    const short* pa1 = p1 + (size_t)gm * 1024 + scol;
    const short* gb = Bt + (size_t)(n0 + srow) * K + scol;

    float inv[16];
#pragma unroll
    for (int h = 0; h < 16; ++h) {
        float l0 = lsum[((size_t)b * 16 + h) * 2048 + q];
        float l1 = lsum[((size_t)(2 + b) * 16 + h) * 2048 + q];
        inv[h] = 1.f / (l0 + l1);
    }

    const int xorv = (lm >> 1) & 7;
    const int rA0 = wm * 64 + lm, rB0 = wn * 32 + lm;

    accf acc[2] = {zero16(), zero16()};

    // prologue: stage iter 0 (B via DMA, A via load+combine+ds_write)
    dma16(gb, &Bs[w * 512]);
    {
        bfr v0 = *(const bfr*)pa0;
        bfr v1 = *(const bfr*)pa1;
        const float iv = inv[0];
        bfr pk;
#pragma unroll
        for (int j = 0; j < 8; ++j)
            pk[j] = f2bf((bf2f(v0[j]) + bf2f(v1[j])) * iv);
        *(bfr*)&As[t * 8] = pk;
    }

#pragma unroll 1
    for (int it = 0; it < NIT; ++it) {
        const int p = it & 1;
        __syncthreads();  // drains buf-p DMA + ds_writes
        bfr v0, v1;
        const bool nxt = (it + 1 < NIT);
        if (nxt) {
            const int ktn = (it + 1) * 32;
            dma16(gb + ktn, &Bs[(1 - p) * 4096 + w * 512]);
            v0 = *(const bfr*)(pa0 + ktn);
            v1 = *(const bfr*)(pa1 + ktn);
        }
        const short* bA = &As[p * 4096];
        const short* bB = &Bs[p * 4096];
#pragma unroll
        for (int kk8 = 0; kk8 < 4; kk8 += 2) {
            bfr a0 = *(const bfr*)&bA[((rA0 * 4 + h2 + kk8) ^ xorv) * 8];
            bfr a1 = *(const bfr*)&bA[(((rA0 + 32) * 4 + h2 + kk8) ^ xorv) * 8];
            bfr b0 = *(const bfr*)&bB[((rB0 * 4 + h2 + kk8) ^ xorv) * 8];
            acc[0] = MFMA32(a0, b0, acc[0]);
            acc[1] = MFMA32(a1, b0, acc[1]);
        }
        if (nxt) {
            const float iv = inv[(it + 1) >> 1];  // h = kt>>6, iter-uniform
            bfr pk;
#pragma unroll
            for (int j = 0; j < 8; ++j)
                pk[j] = f2bf((bf2f(v0[j]) + bf2f(v1[j])) * iv);
            *(bfr*)&As[(1 - p) * 4096 + t * 8] = pk;
        }
    }

    const int n = n0 + wn * 32 + lm;
    const float bn = bias[n];
#pragma unroll
    for (int mt = 0; mt < 2; ++mt) {
        const int mbase = m0 + wm * 64 + mt * 32 + 4 * h2;
#pragma unroll
        for (int r = 0; r < 16; ++r) {
            const int m = mbase + (r & 3) + 8 * (r >> 2);
            out[(size_t)m * 1024 + n] = acc[mt][r] + bn;
        }
    }
}

// ---------- flash attention: LDS-staged K/V + KV-split x2 (unchanged) -----
__global__ __launch_bounds__(256, 3) void attn(
    const short* __restrict__ Qf, const short* __restrict__ Kf,
    const short* __restrict__ Vt, short* __restrict__ part,
    float* __restrict__ lsum) {
    __shared__ short smem[16384];  // 2 bufs x (K 4KB + V 4KB) = 32 KB
    const int bid = blockIdx.x;
    const int hidx = bid & 31, qs = bid >> 5;
    const int split = qs & 1, qb = qs >> 1;
    const int b = hidx >> 4, h = hidx & 15;
    const int lane = threadIdx.x & 63, wv = threadIdx.x >> 6;
    const int lm = lane & 31, h2 = lane >> 5;
    const bool hb = h2 != 0;
    const int q0 = qb * 128 + wv * 32;

    const short* qbase =
        Qf + ((size_t)(hidx * 64 + (q0 >> 5))) * 2048 + lane * 8;
    bfr qf[4];
#pragma unroll
    for (int kc = 0; kc < 4; ++kc) qf[kc] = *(const bfr*)(qbase + kc * 512);

    const short* khead = Kf + (size_t)hidx * 131072 + split * 65536;
    const short* vhead = Vt + (size_t)hidx * 131072 + split * 65536;
    const short* gsrc =
        ((wv < 2) ? (khead + wv * 2048) : (vhead + (wv - 2) * 2048)) + lane * 8;

#pragma unroll
    for (int i = 0; i < 4; ++i)
        dma16(gsrc + i * 512, &smem[wv * 2048 + i * 512]);

    accf oa0 = zero16(), oa1 = zero16();
    float la0 = 0.f, la1 = 0.f;

#pragma unroll 1
    for (int it = 0; it < 16; ++it) {
        const int p = it & 1;
        __syncthreads();  // buf p DMA drained (vmcnt(0) before s_barrier)
        if (it + 1 < 16) {
            const short* gn = gsrc + (size_t)(it + 1) * 4096;
            short* ln = &smem[(1 - p) * 8192 + wv * 2048];
#pragma unroll
            for (int i = 0; i < 4; ++i) dma16(gn + i * 512, ln + i * 512);
        }
        const short* kb = &smem[p * 8192];
        bfr kf0[4], kf1[4], vf0[4], vf1[4];
#pragma unroll
        for (int kc = 0; kc < 4; ++kc) {
            kf0[kc] = *(const bfr*)&kb[kc * 512 + lane * 8];
            kf1[kc] = *(const bfr*)&kb[2048 + kc * 512 + lane * 8];
            vf0[kc] = *(const bfr*)&kb[4096 + kc * 512 + lane * 8];
            vf1[kc] = *(const bfr*)&kb[6144 + kc * 512 + lane * 8];
        }
        accf s0 = zero16(), s1 = zero16();
#pragma unroll
        for (int kc = 0; kc < 4; ++kc) {
            s0 = MFMA32(kf0[kc], qf[kc], s0);
            s1 = MFMA32(kf1[kc], qf[kc], s1);
        }

#pragma unroll
        for (int i = 0; i < 16; ++i) s0[i] = fexp2(s0[i]);
#pragma unroll
        for (int i = 0; i < 16; ++i) s1[i] = fexp2(s1[i]);
#pragma unroll
        for (int i = 0; i < 16; ++i) {
            if (i & 1) la1 += s0[i] + s1[i];
            else       la0 += s0[i] + s1[i];
        }

        // packed half-swap transpose
        bfr pb[4];
#pragma unroll
        for (int kc = 0; kc < 4; ++kc) {
            const accf& s = (kc < 2) ? s0 : s1;
            const int base = 8 * (kc & 1);
            unsigned Lw0 = __builtin_amdgcn_perm(__float_as_uint(s[base + 1]),
                                                 __float_as_uint(s[base + 0]),
                                                 0x07060302u);
            unsigned Lw1 = __builtin_amdgcn_perm(__float_as_uint(s[base + 3]),
                                                 __float_as_uint(s[base + 2]),
                                                 0x07060302u);
            unsigned Hw0 = __builtin_amdgcn_perm(__float_as_uint(s[base + 5]),
                                                 __float_as_uint(s[base + 4]),
                                                 0x07060302u);
            unsigned Hw1 = __builtin_amdgcn_perm(__float_as_uint(s[base + 7]),
                                                 __float_as_uint(s[base + 6]),
                                                 0x07060302u);
            unsigned c0 = hb ? Lw0 : Hw0;
            unsigned c1 = hb ? Lw1 : Hw1;
            unsigned r0 = (unsigned)__shfl_xor((int)c0, 32);
            unsigned r1 = (unsigned)__shfl_xor((int)c1, 32);
            u4v pw = {hb ? r0 : Lw0, hb ? r1 : Lw1,
                      hb ? Hw0 : r0, hb ? Hw1 : r1};
            pb[kc] = __builtin_bit_cast(bfr, pw);
        }

#pragma unroll
        for (int kc = 0; kc < 4; ++kc) {
            oa0 = MFMA32(vf0[kc], pb[kc], oa0);
            oa1 = MFMA32(vf1[kc], pb[kc], oa1);
        }
    }

    float ls = la0 + la1;
    ls += __shfl_xor(ls, 32);
    if (!hb) lsum[((size_t)(split * 2 + b) * 16 + h) * 2048 + q0 + lm] = ls;

    short* orow = part + (size_t)split * 4194304 +
                  (size_t)(b * 2048 + q0 + lm) * 1024 + h * 64;
#pragma unroll
    for (int dt = 0; dt < 2; ++dt) {
        const accf& oa = dt ? oa1 : oa0;
#pragma unroll
        for (int g = 0; g < 4; ++g) {
            const int d0 = dt * 32 + 4 * h2 + 8 * g;
            s4v p = {f2bf(oa[4 * g + 0]), f2bf(oa[4 * g + 1]),
                     f2bf(oa[4 * g + 2]), f2bf(oa[4 * g + 3])};
            *(s4v*)(orow + d0) = p;
        }
    }
}

}  // namespace

extern "C" void kernel_launch(void* const* d_in, const int* in_sizes, int n_in,
                              void* d_out, int out_size, void* d_ws,
                              size_t ws_size, hipStream_t stream) {
    const float* x   = (const float*)d_in[0];
    const float* ctx = (const float*)d_in[1];
    const float* Wq  = (const float*)d_in[2];
    const float* bq  = (const float*)d_in[3];
    const float* Wk  = (const float*)d_in[4];
    const float* bk  = (const float*)d_in[5];
    const float* Wv  = (const float*)d_in[6];
    const float* bv  = (const float*)d_in[7];
    const float* Wo  = (const float*)d_in[8];
    const float* bo  = (const float*)d_in[9];

    short* xb  = (short*)d_ws;
    short* cb  = xb + (size_t)4096 * 1024;
    short* Wqt = cb + (size_t)4096 * 768;
    short* Wkt = Wqt + (size_t)1024 * 1024;
    short* Wvt = Wkt + (size_t)1024 * 768;
    short* Wot = Wvt + (size_t)1024 * 768;
    short* Qf  = Wot + (size_t)1024 * 1024;  // frag-order, pre-scaled
    short* Kf  = Qf + (size_t)4096 * 1024;   // frag-order
    short* Vt  = Kf + (size_t)4096 * 1024;   // frag-order V^T
    short* p0  = Vt + (size_t)4096 * 1024;   // split partials (unnormalized)
    short* p1  = p0 + (size_t)4096 * 1024;
    float* lsum = (float*)(p1 + (size_t)4096 * 1024);  // [2][2][16][2048]

    prep<<<8192, 256, 0, stream>>>(x, ctx, xb, cb, Wq, Wk, Wv, Wo,
                                   Wqt, Wkt, Wvt, Wot);

    const float qscale = 0.125f * 1.44269504088896f;
    gemm_qkv<<<768, 256, 0, stream>>>(xb, cb, Wqt, Wkt, Wvt,
                                      bq, bk, bv, Qf, Kf, Vt, qscale);

    attn<<<1024, 256, 0, stream>>>(Qf, Kf, Vt, p0, lsum);

    gemm_out<<<256, 512, 0, stream>>>(p0, p1, lsum, Wot, bo, (float*)d_out);
}